// Round 10
// baseline (263.823 us; speedup 1.0000x reference)
//
#include <hip/hip_runtime.h>
#include <math.h>

#define BB 8
#define NN 4096
#define TT 8
#define HORQ 8
#define PD 128
#define HID 256
#define NHD 8
#define DH 32
#define FE 56
#define NC2 16
#define CH2 256

typedef __attribute__((ext_vector_type(8))) short short8;
typedef __attribute__((ext_vector_type(4))) float floatx4;
typedef __attribute__((ext_vector_type(2))) float floatx2;
typedef unsigned short ushort_t;

// gelu via tanh-form, exp-based (encoder path)
__device__ __forceinline__ float gelu_fast(float x) {
    float x2 = x * x;
    float y2 = x * fmaf(0.0713551f, x2, 1.5957691f);
    float e = __expf(y2);
    return x - x * __builtin_amdgcn_rcpf(1.f + e);
}

// cheaper gelu for k_fin epilogue: x * sigmoid(1.702x)
__device__ __forceinline__ float gelu_sig(float x) {
    float e = __expf(-1.702f * x);
    return x * __builtin_amdgcn_rcpf(1.f + e);
}

__device__ __forceinline__ float tanh_fast(float x) {
    float e = __expf(2.f * x);
    return 1.f - 2.f * __builtin_amdgcn_rcpf(1.f + e);
}

// fp32 -> bf16 round-to-nearest-even
__device__ __forceinline__ ushort_t f2b(float x) {
    union { float f; unsigned u; } c; c.f = x;
    unsigned r = c.u + 0x7fffu + ((c.u >> 16) & 1u);
    return (ushort_t)(r >> 16);
}
__device__ __forceinline__ float b2f(unsigned hi) {
    union { unsigned u; float f; } c; c.u = hi;
    return c.f;
}

// ---------------- prep: all weight fragments + bk/bv + tq/q (k_fuse folded in) ----
// blocks 0..31  : Wfrag n<512 — inline fused: sum_l qw[k][l]*ipw[l][256+n]
// blocks 32..55 : Wfrag n>=512 from rw1/vw1
// blocks 56..63 : w1frag | 64..71: w2frag | 72: bk/bv | 73..136: tq/q rows
__global__ __launch_bounds__(256) void k_prep(
    const float* __restrict__ qw, const float* __restrict__ qb,
    const float* __restrict__ ipw, const float* __restrict__ ipb,
    const float* __restrict__ rw1, const float* __restrict__ vw1,
    const float* __restrict__ w1, const float* __restrict__ w2,
    const float* __restrict__ aobs, const float* __restrict__ avel,
    const float* __restrict__ te, const float* __restrict__ aw, const float* __restrict__ ab,
    short* __restrict__ Wfrag, short* __restrict__ w1frag, short* __restrict__ w2frag,
    float* __restrict__ bk, float* __restrict__ bv, float* __restrict__ qb_)
{
    __shared__ float af[32];
    __shared__ float tqs[HID];
    int tid = threadIdx.x;
    int blk = blockIdx.x;
    int ks = tid >> 6, lane = tid & 63;
    int quad = lane >> 4, c16 = lane & 15;
    if (blk < 32) {
        // fused Wk/Wv fragment: k = k0..k0+7, n = nt*16+c16 (< 512)
        int nt = blk;
        int n = nt * 16 + c16;
        int k0 = ks * 32 + quad * 8;
        float acc[8];
        #pragma unroll
        for (int j = 0; j < 8; j++) acc[j] = 0.f;
        const float* ipcol = ipw + 256 + n;
        const float* qrow = qw + k0 * 256;
        #pragma unroll 4
        for (int l = 0; l < HID; l++) {
            float ip = ipcol[l * 768];
            #pragma unroll
            for (int j = 0; j < 8; j++) acc[j] = fmaf(qrow[j * 256 + l], ip, acc[j]);
        }
        #pragma unroll
        for (int j = 0; j < 8; j++)
            Wfrag[((nt * 4 + ks) * 64 + lane) * 8 + j] = (short)f2b(acc[j]);
    } else if (blk < 56) {
        int nt = blk;
        int n = nt * 16 + c16;
        for (int j = 0; j < 8; j++) {
            int k = ks * 32 + quad * 8 + j;
            float v = (n < 768) ? rw1[(256 + k) * HID + (n - 512)]
                                : vw1[(256 + k) * PD + (n - 768)];
            Wfrag[((nt * 4 + ks) * 64 + lane) * 8 + j] = (short)f2b(v);
        }
    } else if (blk < 64) {
        if (ks < 2) {
            int nt = blk - 56;
            int n = nt * 16 + c16;
            for (int j = 0; j < 8; j++) {
                int k = ks * 32 + quad * 8 + j;
                float v = (k < FE) ? w1[k * PD + n] : 0.f;
                w1frag[((nt * 2 + ks) * 64 + lane) * 8 + j] = (short)f2b(v);
            }
        }
    } else if (blk < 72) {
        int nt = blk - 64;
        int n = nt * 16 + c16;
        for (int j = 0; j < 8; j++) {
            int k = ks * 32 + quad * 8 + j;
            w2frag[((nt * 4 + ks) * 64 + lane) * 8 + j] = (short)f2b(w2[k * PD + n]);
        }
    } else if (blk == 72) {
        int j = tid;
        float s0 = ipb[256 + j], s1 = 0.f, s2 = 0.f, s3 = 0.f;
        float v0 = ipb[512 + j], v1 = 0.f, v2 = 0.f, v3 = 0.f;
        for (int l = 0; l < HID; l += 4) {
            s0 += qb[l] * ipw[l * 768 + 256 + j];
            s1 += qb[l + 1] * ipw[(l + 1) * 768 + 256 + j];
            s2 += qb[l + 2] * ipw[(l + 2) * 768 + 256 + j];
            s3 += qb[l + 3] * ipw[(l + 3) * 768 + 256 + j];
            v0 += qb[l] * ipw[l * 768 + 512 + j];
            v1 += qb[l + 1] * ipw[(l + 1) * 768 + 512 + j];
            v2 += qb[l + 2] * ipw[(l + 2) * 768 + 512 + j];
            v3 += qb[l + 3] * ipw[(l + 3) * 768 + 512 + j];
        }
        bk[j] = s0 + s1 + s2 + s3;
        bv[j] = v0 + v1 + v2 + v3;
    } else {
        int bh = blk - 73;
        int b = bh >> 3, h = bh & 7;
        if (tid < 32) {
            int t = tid >> 2, m = tid & 3;
            af[tid] = (m < 2) ? aobs[(b * TT + t) * 2 + m] : avel[(b * TT + t) * 2 + (m - 2)];
        }
        __syncthreads();
        float s = te[h * HID + tid] + ab[tid];
        for (int i = 0; i < 32; i++) s += af[i] * aw[i * HID + tid];
        tqs[tid] = s;
        __syncthreads();
        float q0 = ipb[tid], q1 = 0.f, q2 = 0.f, q3 = 0.f;
        for (int i = 0; i < HID; i += 4) {
            q0 += tqs[i] * ipw[i * 768 + tid];
            q1 += tqs[i + 1] * ipw[(i + 1) * 768 + tid];
            q2 += tqs[i + 2] * ipw[(i + 2) * 768 + tid];
            q3 += tqs[i + 3] * ipw[(i + 3) * 768 + tid];
        }
        qb_[(size_t)bh * HID + tid] = q0 + q1 + q2 + q3;
    }
}

// ---------------- fused encoder + projections via bf16 MFMA (R7 layout) ----------------
#define U1_OFF 0
#define XNB_OFF 17408
#define PTB_OFF 26624
#define RXY_OFF 44032
#define MU_OFF 44544
#define RS_OFF 44800
#define SMEM_BYTES 45056

__global__ __launch_bounds__(256) void k_main(
    const float* __restrict__ obs, const int* __restrict__ vis,
    const float* __restrict__ rel,
    const float* __restrict__ lnw, const float* __restrict__ lnb,
    const float* __restrict__ b1, const float* __restrict__ b2,
    const short* __restrict__ Wfrag, const short* __restrict__ w1frag,
    const short* __restrict__ w2frag,
    const float* __restrict__ bk, const float* __restrict__ bv,
    const float* __restrict__ rw1,
    ushort_t* __restrict__ kb, ushort_t* __restrict__ vb,
    ushort_t* __restrict__ P1, ushort_t* __restrict__ P2)
{
    __shared__ __align__(16) char smem[SMEM_BYTES];
    float* xnf = (float*)(smem + U1_OFF);       // [64][57]
    short* h1b = (short*)(smem + U1_OFF);       // [64][136]
    short* xnb = (short*)(smem + XNB_OFF);      // [64][72]
    short* ptb = (short*)(smem + PTB_OFF);      // [64][136]
    float* rxyS = (float*)(smem + RXY_OFF);     // [64][2]
    float* muS = (float*)(smem + MU_OFF);       // [64]
    float* rsS = (float*)(smem + RS_OFF);       // [64]

    int tid = threadIdx.x;
    int w = tid >> 6, lane = tid & 63;
    int quad = lane >> 4, c16 = lane & 15;
    int bn0 = blockIdx.x * 64;

    // phase A: build feat — one (p,t) pair per thread iteration, branchless
    #pragma unroll
    for (int u = 0; u < 2; u++) {
        int pair = tid + u * 256;
        int p = pair >> 3, t = pair & 7;
        int bn = bn0 + p;
        float2 oc = *(const float2*)(obs + (bn * TT + t) * 2);
        int tp = t ? (t - 1) : 0;
        float2 op = *(const float2*)(obs + (bn * TT + tp) * 2);
        float dx = t ? (oc.x - op.x) : 0.f;
        float dy = t ? (oc.y - op.y) : 0.f;
        float vv = (float)vis[bn * TT + t];
        float2 rl = *(const float2*)(rel + bn * 2);
        float* xp = xnf + p * 57 + t * 7;
        xp[0] = oc.x; xp[1] = oc.y; xp[2] = dx; xp[3] = dy;
        xp[4] = vv; xp[5] = rl.x; xp[6] = rl.y;
    }
    if (tid < 128) rxyS[tid] = rel[bn0 * 2 + tid];
    __syncthreads();

    // phase B: LN stats, 4 lanes per point
    {
        int p = tid >> 2, r = tid & 3;
        float s = 0.f, ss = 0.f;
        for (int e = r; e < FE; e += 4) { float v = xnf[p * 57 + e]; s += v; ss += v * v; }
        s += __shfl_xor(s, 1); ss += __shfl_xor(ss, 1);
        s += __shfl_xor(s, 2); ss += __shfl_xor(ss, 2);
        if (r == 0) {
            float mu = s * (1.f / FE);
            float var = ss * (1.f / FE) - mu * mu;
            muS[p] = mu;
            rsS[p] = rsqrtf(var + 1e-5f);
        }
    }
    __syncthreads();

    // phase C: normalize -> bf16 A-layout
    for (int idx = tid; idx < 64 * 64; idx += 256) {
        int p = idx >> 6, e = idx & 63;
        float v = 0.f;
        if (e < FE) v = (xnf[p * 57 + e] - muS[p]) * rsS[p] * lnw[e] + lnb[e];
        xnb[p * 72 + e] = (short)f2b(v);
    }
    __syncthreads();

    // phase D: enc1
    {
        short8 af1[4][2];
        #pragma unroll
        for (int mt = 0; mt < 4; mt++)
            #pragma unroll
            for (int ks = 0; ks < 2; ks++)
                af1[mt][ks] = *(const short8*)(xnb + (mt * 16 + c16) * 72 + ks * 32 + quad * 8);
        #pragma unroll
        for (int ntl = 0; ntl < 2; ntl++) {
            int nt = w * 2 + ntl;
            short8 bf1[2];
            #pragma unroll
            for (int ks = 0; ks < 2; ks++)
                bf1[ks] = *(const short8*)(w1frag + ((nt * 2 + ks) * 64 + lane) * 8);
            int col = nt * 16 + c16;
            float bb = b1[col];
            #pragma unroll
            for (int mt = 0; mt < 4; mt++) {
                floatx4 acc = {0.f, 0.f, 0.f, 0.f};
                acc = __builtin_amdgcn_mfma_f32_16x16x32_bf16(af1[mt][0], bf1[0], acc, 0, 0, 0);
                acc = __builtin_amdgcn_mfma_f32_16x16x32_bf16(af1[mt][1], bf1[1], acc, 0, 0, 0);
                #pragma unroll
                for (int r = 0; r < 4; r++) {
                    int row = mt * 16 + quad * 4 + r;
                    h1b[row * 136 + col] = (short)f2b(gelu_fast(acc[r] + bb));
                }
            }
        }
    }
    __syncthreads();

    // phase E: enc2
    {
        short8 af2[4][4];
        #pragma unroll
        for (int mt = 0; mt < 4; mt++)
            #pragma unroll
            for (int ks = 0; ks < 4; ks++)
                af2[mt][ks] = *(const short8*)(h1b + (mt * 16 + c16) * 136 + ks * 32 + quad * 8);
        #pragma unroll
        for (int ntl = 0; ntl < 2; ntl++) {
            int nt = w * 2 + ntl;
            short8 bf2[4];
            #pragma unroll
            for (int ks = 0; ks < 4; ks++)
                bf2[ks] = *(const short8*)(w2frag + ((nt * 4 + ks) * 64 + lane) * 8);
            int col = nt * 16 + c16;
            float bb = b2[col];
            #pragma unroll
            for (int mt = 0; mt < 4; mt++) {
                floatx4 acc = {0.f, 0.f, 0.f, 0.f};
                #pragma unroll
                for (int ks = 0; ks < 4; ks++)
                    acc = __builtin_amdgcn_mfma_f32_16x16x32_bf16(af2[mt][ks], bf2[ks], acc, 0, 0, 0);
                #pragma unroll
                for (int r = 0; r < 4; r++) {
                    int row = mt * 16 + quad * 4 + r;
                    ptb[row * 136 + col] = (short)f2b(gelu_fast(acc[r] + bb));
                }
            }
        }
    }
    __syncthreads();

    // phase F: big GEMM [64x128] @ [128x896], bf16 outputs
    {
        short8 af[4][4];
        #pragma unroll
        for (int mt = 0; mt < 4; mt++)
            #pragma unroll
            for (int ks = 0; ks < 4; ks++)
                af[mt][ks] = *(const short8*)(ptb + (mt * 16 + c16) * 136 + ks * 32 + quad * 8);
        for (int i = 0; i < 14; i++) {
            int nt = w + i * 4;
            short8 bf[4];
            #pragma unroll
            for (int ks = 0; ks < 4; ks++)
                bf[ks] = *(const short8*)(Wfrag + ((nt * 4 + ks) * 64 + lane) * 8);
            floatx4 acc[4];
            #pragma unroll
            for (int mt = 0; mt < 4; mt++) {
                acc[mt] = (floatx4){0.f, 0.f, 0.f, 0.f};
                #pragma unroll
                for (int ks = 0; ks < 4; ks++)
                    acc[mt] = __builtin_amdgcn_mfma_f32_16x16x32_bf16(af[mt][ks], bf[ks], acc[mt], 0, 0, 0);
            }
            int n = nt * 16 + c16;
            if (nt < 16) {
                float bb = bk[n];
                #pragma unroll
                for (int mt = 0; mt < 4; mt++)
                    #pragma unroll
                    for (int r = 0; r < 4; r++) {
                        int row = mt * 16 + quad * 4 + r;
                        kb[(size_t)(bn0 + row) * HID + n] = f2b(acc[mt][r] + bb);
                    }
            } else if (nt < 32) {
                int j = n - 256;
                float bb = bv[j];
                #pragma unroll
                for (int mt = 0; mt < 4; mt++)
                    #pragma unroll
                    for (int r = 0; r < 4; r++) {
                        int row = mt * 16 + quad * 4 + r;
                        vb[(size_t)(bn0 + row) * HID + j] = f2b(acc[mt][r] + bb);
                    }
            } else if (nt < 48) {
                int j = n - 512;
                float wr0 = rw1[384 * HID + j], wr1 = rw1[385 * HID + j];
                #pragma unroll
                for (int mt = 0; mt < 4; mt++)
                    #pragma unroll
                    for (int r = 0; r < 4; r++) {
                        int row = mt * 16 + quad * 4 + r;
                        P1[(size_t)(bn0 + row) * HID + j] =
                            f2b(acc[mt][r] + rxyS[row * 2] * wr0 + rxyS[row * 2 + 1] * wr1);
                    }
            } else {
                int j = n - 768;
                #pragma unroll
                for (int mt = 0; mt < 4; mt++)
                    #pragma unroll
                    for (int r = 0; r < 4; r++) {
                        int row = mt * 16 + quad * 4 + r;
                        P2[(size_t)(bn0 + row) * PD + j] = f2b(acc[mt][r]);
                    }
            }
        }
    }
}

// ---------------- attention: QK with q-in-registers, bf16 K/V ----------------
__global__ __launch_bounds__(256) void k_att(
    const float* __restrict__ qbuf, const ushort_t* __restrict__ kb, const ushort_t* __restrict__ vbuf,
    float* __restrict__ pm, float* __restrict__ pl, float* __restrict__ po)
{
    __shared__ float sc[8][CH2];
    __shared__ float pos[8][8][DH];
    int tid = threadIdx.x;
    int bidx = blockIdx.x;
    int c = bidx & (NC2 - 1);
    int head = (bidx >> 4) & 7;
    int b = bidx >> 7;
    const float scale = 0.17677669529663688110f;
    {
        int qq = tid >> 5, ln = tid & 31;
        float qr[DH];
        const float* qp = qbuf + (size_t)(b * HORQ + qq) * HID + head * DH;
        #pragma unroll
        for (int u = 0; u < 8; u++) {
            float4 f = *(const float4*)(qp + u * 4);
            qr[u * 4] = f.x; qr[u * 4 + 1] = f.y; qr[u * 4 + 2] = f.z; qr[u * 4 + 3] = f.w;
        }
        #pragma unroll
        for (int i = 0; i < 8; i++) {
            int nn = ln + 32 * i;
            const ushort_t* kp = kb + (size_t)(b * NN + c * CH2 + nn) * HID + head * DH;
            float s = 0.f;
            #pragma unroll
            for (int u = 0; u < 4; u++) {
                uint4 q = *(const uint4*)(kp + u * 8);
                unsigned wd[4] = {q.x, q.y, q.z, q.w};
                #pragma unroll
                for (int t2 = 0; t2 < 4; t2++) {
                    s += qr[u * 8 + 2 * t2]     * b2f(wd[t2] << 16);
                    s += qr[u * 8 + 2 * t2 + 1] * b2f(wd[t2] & 0xffff0000u);
                }
            }
            sc[qq][nn] = s * scale;
        }
    }
    __syncthreads();
    int qq = tid >> 5, r = tid & 31;
    float mx = -1e30f;
    #pragma unroll
    for (int nn = r; nn < CH2; nn += 32) mx = fmaxf(mx, sc[qq][nn]);
    #pragma unroll
    for (int m = 16; m; m >>= 1) mx = fmaxf(mx, __shfl_xor(mx, m, 32));
    float sum = 0.f;
    #pragma unroll
    for (int nn = r; nn < CH2; nn += 32) { float e = __expf(sc[qq][nn] - mx); sc[qq][nn] = e; sum += e; }
    #pragma unroll
    for (int m = 16; m; m >>= 1) sum += __shfl_xor(sum, m, 32);
    if (r == 0) { pm[bidx * 8 + qq] = mx; pl[bidx * 8 + qq] = sum; }
    __syncthreads();
    {
        int g = tid >> 5, d = tid & 31;
        float oacc[8];
        #pragma unroll
        for (int q2 = 0; q2 < 8; q2++) oacc[q2] = 0.f;
        const ushort_t* vp = vbuf + ((size_t)(b * NN + c * CH2 + g * 32)) * HID + head * DH + d;
        for (int i = 0; i < 32; i++) {
            float v = b2f(((unsigned)vp[(size_t)i * HID]) << 16);
            int nn = g * 32 + i;
            #pragma unroll
            for (int q2 = 0; q2 < 8; q2++) oacc[q2] += sc[q2][nn] * v;
        }
        #pragma unroll
        for (int q2 = 0; q2 < 8; q2++) pos[g][q2][d] = oacc[q2];
    }
    __syncthreads();
    {
        int q2 = tid >> 5, d = tid & 31;
        float o = 0.f;
        #pragma unroll
        for (int gg = 0; gg < 8; gg++) o += pos[gg][q2][d];
        po[(size_t)(bidx * 8 + q2) * DH + d] = o;
    }
}

// ---------------- merged: combine chunks + future + row heads ----------------
__global__ __launch_bounds__(256) void k_attfut(
    const float* __restrict__ pm, const float* __restrict__ pl, const float* __restrict__ po,
    const float* __restrict__ opw, const float* __restrict__ opb,
    const float* __restrict__ rw1, const float* __restrict__ rb1,
    const float* __restrict__ vw1, const float* __restrict__ vb1,
    const float* __restrict__ shw, const float* __restrict__ shb,
    const float* __restrict__ ahw, const float* __restrict__ ahb,
    float* __restrict__ F1, float* __restrict__ F2, float* __restrict__ dl, float* __restrict__ sem)
{
    __shared__ float orow[HID], fut[HID];
    int tid = threadIdx.x;
    int b = blockIdx.x >> 3, qq = blockIdx.x & 7;
    {
        int head = tid >> 5, d = tid & 31;
        int base = b * 1024 + head * 128 + qq;
        float M = -1e30f;
        #pragma unroll
        for (int c = 0; c < NC2; c++) M = fmaxf(M, pm[base + c * 8]);
        float L = 0.f, o = 0.f;
        #pragma unroll
        for (int c = 0; c < NC2; c++) {
            float wgt = __expf(pm[base + c * 8] - M);
            L += wgt * pl[base + c * 8];
            o += wgt * po[(size_t)(base + c * 8) * DH + d];
        }
        orow[head * DH + d] = o / L;
    }
    __syncthreads();
    {
        float a0 = opb[tid], a1 = 0.f, a2 = 0.f, a3 = 0.f;
        for (int i = 0; i < HID; i += 4) {
            a0 += orow[i] * opw[i * HID + tid];
            a1 += orow[i + 1] * opw[(i + 1) * HID + tid];
            a2 += orow[i + 2] * opw[(i + 2) * HID + tid];
            a3 += orow[i + 3] * opw[(i + 3) * HID + tid];
        }
        fut[tid] = a0 + a1 + a2 + a3;
    }
    __syncthreads();
    int bh = b * HORQ + qq;
    {
        float a0 = rb1[tid], a1 = 0.f, a2 = 0.f, a3 = 0.f;
        for (int i = 0; i < HID; i += 4) {
            a0 += fut[i] * rw1[i * HID + tid];
            a1 += fut[i + 1] * rw1[(i + 1) * HID + tid];
            a2 += fut[i + 2] * rw1[(i + 2) * HID + tid];
            a3 += fut[i + 3] * rw1[(i + 3) * HID + tid];
        }
        F1[(size_t)bh * HID + tid] = a0 + a1 + a2 + a3;
    }
    if (tid < PD) {
        float a0 = vb1[tid], a1 = 0.f, a2 = 0.f, a3 = 0.f;
        for (int i = 0; i < HID; i += 4) {
            a0 += fut[i] * vw1[i * PD + tid];
            a1 += fut[i + 1] * vw1[(i + 1) * PD + tid];
            a2 += fut[i + 2] * vw1[(i + 2) * PD + tid];
            a3 += fut[i + 3] * vw1[(i + 3) * PD + tid];
        }
        F2[(size_t)bh * PD + tid] = a0 + a1 + a2 + a3;
    }
    {
        int j = tid >> 3, part = tid & 7;
        float s3 = 0.f;
        for (int i = part * 32; i < part * 32 + 32; i++) s3 += fut[i] * shw[i * 32 + j];
        s3 += __shfl_xor(s3, 1);
        s3 += __shfl_xor(s3, 2);
        s3 += __shfl_xor(s3, 4);
        if (part == 0) sem[bh * 32 + j] = s3 + shb[j];
    }
    if (tid < 128) {
        int j = tid >> 6, part = tid & 63;
        float a = 0.f;
        #pragma unroll
        for (int u = 0; u < 4; u++) { int i = part * 4 + u; a += fut[i] * ahw[i * 2 + j]; }
        #pragma unroll
        for (int m = 32; m; m >>= 1) a += __shfl_xor(a, m);
        if (part == 0) dl[bh * 2 + j] = 0.1f * tanhf(a + ahb[j]);
    }
}

// ---------------- anchor cumsum ----------------
__global__ void k_cum(const float* __restrict__ aobs, const float* __restrict__ dl, float* __restrict__ out0)
{
    int tid = threadIdx.x;
    if (tid < 16) {
        int b = tid >> 1, c = tid & 1;
        float acc = aobs[(b * TT + 7) * 2 + c];
        for (int h = 0; h < HORQ; h++) {
            acc += dl[(b * HORQ + h) * 2 + c];
            out0[(b * HORQ + h) * 2 + c] = acc;
        }
    }
}

// ---------------- final epilogue: 4 points per wave (16 lanes/point), low-VGPR ----
// Persistent per-lane state: p1f[16]+p2f[8] only. Weights re-loaded per h (L1-hit).
__global__ __launch_bounds__(256) void k_fin(
    const float* __restrict__ F1, const float* __restrict__ F2,
    const ushort_t* __restrict__ P1, const ushort_t* __restrict__ P2,
    const float* __restrict__ rw2, const float* __restrict__ rb2,
    const float* __restrict__ vw2, const float* __restrict__ vb2,
    const float* __restrict__ ap,
    float* __restrict__ out1, float* __restrict__ out2)
{
    int tid = threadIdx.x;
    int g = tid >> 4;     // point group in block (0..15)
    int l = tid & 15;
    int bn = blockIdx.x * 16 + g;
    int b = bn >> 12;     // block-uniform

    // P1 slice: 16 consecutive bf16 (persistent)
    float p1f[16];
    {
        const uint4* p1p = (const uint4*)(P1 + (size_t)bn * HID + l * 16);
        #pragma unroll
        for (int c = 0; c < 2; c++) {
            uint4 q = p1p[c];
            unsigned wd[4] = {q.x, q.y, q.z, q.w};
            #pragma unroll
            for (int u = 0; u < 4; u++) {
                p1f[c * 8 + 2 * u]     = b2f(wd[u] << 16);
                p1f[c * 8 + 2 * u + 1] = b2f(wd[u] & 0xffff0000u);
            }
        }
    }
    // P2 slice: 8 consecutive bf16 (persistent)
    float p2f[8];
    {
        uint4 q = *(const uint4*)(P2 + (size_t)bn * PD + l * 8);
        unsigned wd[4] = {q.x, q.y, q.z, q.w};
        #pragma unroll
        for (int u = 0; u < 4; u++) {
            p2f[2 * u]     = b2f(wd[u] << 16);
            p2f[2 * u + 1] = b2f(wd[u] & 0xffff0000u);
        }
    }

    const float4* rwp = (const float4*)(rw2 + l * 32);  // interleaved (w0,w1) pairs
    const float4* vwp = (const float4*)(vw2 + l * 8);
    float rb20 = rb2[0], rb21 = rb2[1], vb20 = vb2[0];

    for (int h = 0; h < HORQ; h++) {
        const float* f1p = F1 + (size_t)(b * HORQ + h) * HID + l * 16;
        const float* f2p = F2 + (size_t)(b * HORQ + h) * PD + l * 8;
        floatx2 s01 = {0.f, 0.f};
        float sv = 0.f;
        #pragma unroll
        for (int c = 0; c < 4; c++) {
            float4 f = *(const float4*)(f1p + c * 4);
            float4 ra = rwp[c * 2];       // w0[j0],w1[j0],w0[j0+1],w1[j0+1]
            float4 rb = rwp[c * 2 + 1];   // j0+2, j0+3
            float g0 = gelu_sig(f.x + p1f[c * 4 + 0]);
            float g1 = gelu_sig(f.y + p1f[c * 4 + 1]);
            float g2 = gelu_sig(f.z + p1f[c * 4 + 2]);
            float g3 = gelu_sig(f.w + p1f[c * 4 + 3]);
            s01 += (floatx2){g0, g0} * (floatx2){ra.x, ra.y};
            s01 += (floatx2){g1, g1} * (floatx2){ra.z, ra.w};
            s01 += (floatx2){g2, g2} * (floatx2){rb.x, rb.y};
            s01 += (floatx2){g3, g3} * (floatx2){rb.z, rb.w};
        }
        #pragma unroll
        for (int c = 0; c < 2; c++) {
            float4 f = *(const float4*)(f2p + c * 4);
            float4 wv4 = vwp[c];
            sv += gelu_sig(f.x + p2f[c * 4 + 0]) * wv4.x;
            sv += gelu_sig(f.y + p2f[c * 4 + 1]) * wv4.y;
            sv += gelu_sig(f.z + p2f[c * 4 + 2]) * wv4.z;
            sv += gelu_sig(f.w + p2f[c * 4 + 3]) * wv4.w;
        }
        float s0 = s01.x, s1 = s01.y;
        #pragma unroll
        for (int m = 8; m; m >>= 1) {
            s0 += __shfl_xor(s0, m, 16);
            s1 += __shfl_xor(s1, m, 16);
            sv += __shfl_xor(sv, m, 16);
        }
        if (l == 0) {
            float rx = 0.1f * tanh_fast(s0 + rb20);
            float ry = 0.1f * tanh_fast(s1 + rb21);
            int bh = b * HORQ + h;
            out1[((size_t)bn * HORQ + h) * 2 + 0] = ap[bh * 2 + 0] + rx;
            out1[((size_t)bn * HORQ + h) * 2 + 1] = ap[bh * 2 + 1] + ry;
            out2[(size_t)bn * HORQ + h] = sv + vb20;
        }
    }
}

extern "C" void kernel_launch(void* const* d_in, const int* in_sizes, int n_in,
                              void* d_out, int out_size, void* d_ws, size_t ws_size,
                              hipStream_t stream)
{
    const float* obs  = (const float*)d_in[0];
    const int*   vis  = (const int*)d_in[1];
    const float* rel  = (const float*)d_in[2];
    const float* aobs = (const float*)d_in[3];
    const float* avel = (const float*)d_in[4];
    const float* lnw = (const float*)d_in[6];
    const float* lnb = (const float*)d_in[7];
    const float* ew1 = (const float*)d_in[8];
    const float* eb1 = (const float*)d_in[9];
    const float* ew2 = (const float*)d_in[10];
    const float* eb2 = (const float*)d_in[11];
    const float* te  = (const float*)d_in[12];
    const float* aw  = (const float*)d_in[13];
    const float* ab  = (const float*)d_in[14];
    const float* qw  = (const float*)d_in[15];
    const float* qbias = (const float*)d_in[16];
    const float* ipw = (const float*)d_in[17];
    const float* ipb = (const float*)d_in[18];
    const float* opw = (const float*)d_in[19];
    const float* opb = (const float*)d_in[20];
    const float* ahw = (const float*)d_in[21];
    const float* ahb = (const float*)d_in[22];
    const float* rw1 = (const float*)d_in[23];
    const float* rb1 = (const float*)d_in[24];
    const float* rw2 = (const float*)d_in[25];
    const float* rb2 = (const float*)d_in[26];
    const float* vw1 = (const float*)d_in[27];
    const float* vb1 = (const float*)d_in[28];
    const float* vw2 = (const float*)d_in[29];
    const float* vb2 = (const float*)d_in[30];
    const float* shw = (const float*)d_in[31];
    const float* shb = (const float*)d_in[32];

    float* W = (float*)d_ws;
    size_t o = 0;
    float* bk  = W + o; o += HID;
    float* bv  = W + o; o += HID;
    float* qb_ = W + o; o += (size_t)BB * HORQ * HID;
    float* F1  = W + o; o += (size_t)BB * HORQ * HID;
    float* F2  = W + o; o += (size_t)BB * HORQ * PD;
    float* dl  = W + o; o += (size_t)BB * HORQ * 2;
    float* pm  = W + o; o += (size_t)BB * NHD * NC2 * 8;
    float* pl  = W + o; o += (size_t)BB * NHD * NC2 * 8;
    float* po  = W + o; o += (size_t)BB * NHD * NC2 * 8 * DH;
    ushort_t* kb   = (ushort_t*)(W + o); o += (size_t)BB * NN * HID / 2;
    ushort_t* vbuf = (ushort_t*)(W + o); o += (size_t)BB * NN * HID / 2;
    ushort_t* P1   = (ushort_t*)(W + o); o += (size_t)BB * NN * HID / 2;
    ushort_t* P2   = (ushort_t*)(W + o); o += (size_t)BB * NN * PD / 2;
    short* Sf = (short*)(W + o);
    short* Wfrag  = Sf;
    short* w1frag = Sf + 114688;
    short* w2frag = Sf + 114688 + 8192;

    float* out0 = (float*)d_out;
    float* out1 = out0 + BB * HORQ * 2;
    float* out2 = out1 + (size_t)BB * NN * HORQ * 2;
    float* out3 = out2 + (size_t)BB * NN * HORQ;

    k_prep<<<137, 256, 0, stream>>>(qw, qbias, ipw, ipb, rw1, vw1, ew1, ew2,
                                    aobs, avel, te, aw, ab,
                                    Wfrag, w1frag, w2frag, bk, bv, qb_);
    k_main<<<BB * NN / 64, 256, 0, stream>>>(obs, vis, rel, lnw, lnb, eb1, eb2,
                                             Wfrag, w1frag, w2frag, bk, bv, rw1,
                                             kb, vbuf, P1, P2);
    k_att<<<BB * NHD * NC2, 256, 0, stream>>>(qb_, kb, vbuf, pm, pl, po);
    k_attfut<<<BB * HORQ, 256, 0, stream>>>(pm, pl, po, opw, opb, rw1, rb1, vw1, vb1,
                                            shw, shb, ahw, ahb, F1, F2, dl, out3);
    k_cum<<<1, 64, 0, stream>>>(aobs, dl, out0);
    k_fin<<<BB * NN / 16, 256, 0, stream>>>(F1, F2, P1, P2, rw2, rb2, vw2, vb2,
                                            out0, out1, out2);
}

// Round 11
// 263.462 us; speedup vs baseline: 1.0014x; 1.0014x over previous
//
#include <hip/hip_runtime.h>
#include <math.h>

#define BB 8
#define NN 4096
#define TT 8
#define HORQ 8
#define PD 128
#define HID 256
#define NHD 8
#define DH 32
#define FE 56
#define NC2 16
#define CH2 256

typedef __attribute__((ext_vector_type(8))) short short8;
typedef __attribute__((ext_vector_type(4))) float floatx4;
typedef __attribute__((ext_vector_type(2))) float floatx2;
typedef unsigned short ushort_t;

// gelu via tanh-form, exp-based (encoder path)
__device__ __forceinline__ float gelu_fast(float x) {
    float x2 = x * x;
    float y2 = x * fmaf(0.0713551f, x2, 1.5957691f);
    float e = __expf(y2);
    return x - x * __builtin_amdgcn_rcpf(1.f + e);
}

// cheaper gelu for k_fin epilogue: x * sigmoid(1.702x)
__device__ __forceinline__ float gelu_sig(float x) {
    float e = __expf(-1.702f * x);
    return x * __builtin_amdgcn_rcpf(1.f + e);
}

__device__ __forceinline__ float tanh_fast(float x) {
    float e = __expf(2.f * x);
    return 1.f - 2.f * __builtin_amdgcn_rcpf(1.f + e);
}

// fp32 -> bf16 round-to-nearest-even
__device__ __forceinline__ ushort_t f2b(float x) {
    union { float f; unsigned u; } c; c.f = x;
    unsigned r = c.u + 0x7fffu + ((c.u >> 16) & 1u);
    return (ushort_t)(r >> 16);
}
__device__ __forceinline__ float b2f(unsigned hi) {
    union { unsigned u; float f; } c; c.u = hi;
    return c.f;
}

// ---------------- fuse query_w into k/v projections (fp32, 4-acc chains) ----------------
__global__ __launch_bounds__(256) void k_fuse(
    const float* __restrict__ qw, const float* __restrict__ qb,
    const float* __restrict__ ipw, const float* __restrict__ ipb,
    float* __restrict__ Wk, float* __restrict__ Wv,
    float* __restrict__ bk, float* __restrict__ bv)
{
    int j = threadIdx.x;
    int blk = blockIdx.x;
    const float* src = (blk < PD) ? (qw + blk * HID) : qb;
    float sk0 = 0.f, sk1 = 0.f, sk2 = 0.f, sk3 = 0.f;
    float sv0 = 0.f, sv1 = 0.f, sv2 = 0.f, sv3 = 0.f;
    for (int l = 0; l < HID; l += 4) {
        float w0 = src[l], w1 = src[l + 1], w2 = src[l + 2], w3 = src[l + 3];
        sk0 += w0 * ipw[l * 768 + 256 + j];
        sk1 += w1 * ipw[(l + 1) * 768 + 256 + j];
        sk2 += w2 * ipw[(l + 2) * 768 + 256 + j];
        sk3 += w3 * ipw[(l + 3) * 768 + 256 + j];
        sv0 += w0 * ipw[l * 768 + 512 + j];
        sv1 += w1 * ipw[(l + 1) * 768 + 512 + j];
        sv2 += w2 * ipw[(l + 2) * 768 + 512 + j];
        sv3 += w3 * ipw[(l + 3) * 768 + 512 + j];
    }
    float sk = sk0 + sk1 + sk2 + sk3, sv = sv0 + sv1 + sv2 + sv3;
    if (blk < PD) {
        Wk[blk * HID + j] = sk;
        Wv[blk * HID + j] = sv;
    } else {
        bk[j] = sk + ipb[256 + j];
        bv[j] = sv + ipb[512 + j];
    }
}

// ---------------- pack weight fragments + tq/q rows ----------------
__global__ __launch_bounds__(256) void k_prep(
    const float* __restrict__ Wk, const float* __restrict__ Wv,
    const float* __restrict__ rw1, const float* __restrict__ vw1,
    const float* __restrict__ w1, const float* __restrict__ w2,
    const float* __restrict__ aobs, const float* __restrict__ avel,
    const float* __restrict__ te, const float* __restrict__ aw, const float* __restrict__ ab,
    const float* __restrict__ ipw, const float* __restrict__ ipb,
    short* __restrict__ Wfrag, short* __restrict__ w1frag, short* __restrict__ w2frag,
    float* __restrict__ qb_)
{
    __shared__ float af[32];
    __shared__ float tqs[HID];
    int tid = threadIdx.x;
    int blk = blockIdx.x;
    int ks = tid >> 6, lane = tid & 63;
    int quad = lane >> 4, c16 = lane & 15;
    if (blk < 56) {
        int nt = blk;
        int n = nt * 16 + c16;
        for (int j = 0; j < 8; j++) {
            int k = ks * 32 + quad * 8 + j;
            float v;
            if (n < 256)      v = Wk[k * HID + n];
            else if (n < 512) v = Wv[k * HID + (n - 256)];
            else if (n < 768) v = rw1[(256 + k) * HID + (n - 512)];
            else              v = vw1[(256 + k) * PD + (n - 768)];
            Wfrag[((nt * 4 + ks) * 64 + lane) * 8 + j] = (short)f2b(v);
        }
    } else if (blk < 64) {
        if (ks < 2) {
            int nt = blk - 56;
            int n = nt * 16 + c16;
            for (int j = 0; j < 8; j++) {
                int k = ks * 32 + quad * 8 + j;
                float v = (k < FE) ? w1[k * PD + n] : 0.f;
                w1frag[((nt * 2 + ks) * 64 + lane) * 8 + j] = (short)f2b(v);
            }
        }
    } else if (blk < 72) {
        int nt = blk - 64;
        int n = nt * 16 + c16;
        for (int j = 0; j < 8; j++) {
            int k = ks * 32 + quad * 8 + j;
            w2frag[((nt * 4 + ks) * 64 + lane) * 8 + j] = (short)f2b(w2[k * PD + n]);
        }
    } else {
        int bh = blk - 72;
        int b = bh >> 3, h = bh & 7;
        if (tid < 32) {
            int t = tid >> 2, m = tid & 3;
            af[tid] = (m < 2) ? aobs[(b * TT + t) * 2 + m] : avel[(b * TT + t) * 2 + (m - 2)];
        }
        __syncthreads();
        float s = te[h * HID + tid] + ab[tid];
        for (int i = 0; i < 32; i++) s += af[i] * aw[i * HID + tid];
        tqs[tid] = s;
        __syncthreads();
        float q0 = ipb[tid], q1 = 0.f, q2 = 0.f, q3 = 0.f;
        for (int i = 0; i < HID; i += 4) {
            q0 += tqs[i] * ipw[i * 768 + tid];
            q1 += tqs[i + 1] * ipw[(i + 1) * 768 + tid];
            q2 += tqs[i + 2] * ipw[(i + 2) * 768 + tid];
            q3 += tqs[i + 3] * ipw[(i + 3) * 768 + tid];
        }
        qb_[(size_t)bh * HID + tid] = q0 + q1 + q2 + q3;
    }
}

// ---------------- fused encoder + projections via bf16 MFMA (32-point tiles) -------
// 32 points/block, 1024 blocks -> 4 blocks/CU (was 2). Same per-point work.
#define U1_OFF 0         // xnf fp32 [32][57] (7296 B) UNION h1b bf16 [32][136] (8704 B)
#define XNB_OFF 8704     // xnb bf16 [32][72] = 4608 B
#define PTB_OFF 13312    // ptb bf16 [32][136] = 8704 B
#define RXY_OFF 22016    // [32][2] fp32 = 256 B
#define MU_OFF 22272     // 128 B
#define RS_OFF 22400     // 128 B
#define SMEM_BYTES 22528

__global__ __launch_bounds__(256) void k_main(
    const float* __restrict__ obs, const int* __restrict__ vis,
    const float* __restrict__ rel,
    const float* __restrict__ lnw, const float* __restrict__ lnb,
    const float* __restrict__ b1, const float* __restrict__ b2,
    const short* __restrict__ Wfrag, const short* __restrict__ w1frag,
    const short* __restrict__ w2frag,
    const float* __restrict__ bk, const float* __restrict__ bv,
    const float* __restrict__ rw1,
    ushort_t* __restrict__ kb, ushort_t* __restrict__ vb,
    ushort_t* __restrict__ P1, ushort_t* __restrict__ P2)
{
    __shared__ __align__(16) char smem[SMEM_BYTES];
    float* xnf = (float*)(smem + U1_OFF);       // [32][57]
    short* h1b = (short*)(smem + U1_OFF);       // [32][136]
    short* xnb = (short*)(smem + XNB_OFF);      // [32][72]
    short* ptb = (short*)(smem + PTB_OFF);      // [32][136]
    float* rxyS = (float*)(smem + RXY_OFF);     // [32][2]
    float* muS = (float*)(smem + MU_OFF);       // [32]
    float* rsS = (float*)(smem + RS_OFF);       // [32]

    int tid = threadIdx.x;
    int w = tid >> 6, lane = tid & 63;
    int quad = lane >> 4, c16 = lane & 15;
    int bn0 = blockIdx.x * 32;

    // phase A: one (p,t) pair per thread, branchless
    {
        int p = tid >> 3, t = tid & 7;
        int bn = bn0 + p;
        float2 oc = *(const float2*)(obs + (bn * TT + t) * 2);
        int tp = t ? (t - 1) : 0;
        float2 op = *(const float2*)(obs + (bn * TT + tp) * 2);
        float dx = t ? (oc.x - op.x) : 0.f;
        float dy = t ? (oc.y - op.y) : 0.f;
        float vv = (float)vis[bn * TT + t];
        float2 rl = *(const float2*)(rel + bn * 2);
        float* xp = xnf + p * 57 + t * 7;
        xp[0] = oc.x; xp[1] = oc.y; xp[2] = dx; xp[3] = dy;
        xp[4] = vv; xp[5] = rl.x; xp[6] = rl.y;
    }
    if (tid < 64) rxyS[tid] = rel[bn0 * 2 + tid];
    __syncthreads();

    // phase B: LN stats, 8 lanes per point
    {
        int p = tid >> 3, r = tid & 7;
        float s = 0.f, ss = 0.f;
        for (int e = r; e < FE; e += 8) { float v = xnf[p * 57 + e]; s += v; ss += v * v; }
        s += __shfl_xor(s, 1); ss += __shfl_xor(ss, 1);
        s += __shfl_xor(s, 2); ss += __shfl_xor(ss, 2);
        s += __shfl_xor(s, 4); ss += __shfl_xor(ss, 4);
        if (r == 0) {
            float mu = s * (1.f / FE);
            float var = ss * (1.f / FE) - mu * mu;
            muS[p] = mu;
            rsS[p] = rsqrtf(var + 1e-5f);
        }
    }
    __syncthreads();

    // phase C: normalize -> bf16 A-layout (rows padded to 72)
    for (int idx = tid; idx < 32 * 64; idx += 256) {
        int p = idx >> 6, e = idx & 63;
        float v = 0.f;
        if (e < FE) v = (xnf[p * 57 + e] - muS[p]) * rsS[p] * lnw[e] + lnb[e];
        xnb[p * 72 + e] = (short)f2b(v);
    }
    __syncthreads();

    // phase D: enc1 (2 m-tiles)
    {
        short8 af1[2][2];
        #pragma unroll
        for (int mt = 0; mt < 2; mt++)
            #pragma unroll
            for (int ks = 0; ks < 2; ks++)
                af1[mt][ks] = *(const short8*)(xnb + (mt * 16 + c16) * 72 + ks * 32 + quad * 8);
        #pragma unroll
        for (int ntl = 0; ntl < 2; ntl++) {
            int nt = w * 2 + ntl;
            short8 bf1[2];
            #pragma unroll
            for (int ks = 0; ks < 2; ks++)
                bf1[ks] = *(const short8*)(w1frag + ((nt * 2 + ks) * 64 + lane) * 8);
            int col = nt * 16 + c16;
            float bb = b1[col];
            #pragma unroll
            for (int mt = 0; mt < 2; mt++) {
                floatx4 acc = {0.f, 0.f, 0.f, 0.f};
                acc = __builtin_amdgcn_mfma_f32_16x16x32_bf16(af1[mt][0], bf1[0], acc, 0, 0, 0);
                acc = __builtin_amdgcn_mfma_f32_16x16x32_bf16(af1[mt][1], bf1[1], acc, 0, 0, 0);
                #pragma unroll
                for (int r = 0; r < 4; r++) {
                    int row = mt * 16 + quad * 4 + r;
                    h1b[row * 136 + col] = (short)f2b(gelu_fast(acc[r] + bb));
                }
            }
        }
    }
    __syncthreads();

    // phase E: enc2
    {
        short8 af2[2][4];
        #pragma unroll
        for (int mt = 0; mt < 2; mt++)
            #pragma unroll
            for (int ks = 0; ks < 4; ks++)
                af2[mt][ks] = *(const short8*)(h1b + (mt * 16 + c16) * 136 + ks * 32 + quad * 8);
        #pragma unroll
        for (int ntl = 0; ntl < 2; ntl++) {
            int nt = w * 2 + ntl;
            short8 bf2[4];
            #pragma unroll
            for (int ks = 0; ks < 4; ks++)
                bf2[ks] = *(const short8*)(w2frag + ((nt * 4 + ks) * 64 + lane) * 8);
            int col = nt * 16 + c16;
            float bb = b2[col];
            #pragma unroll
            for (int mt = 0; mt < 2; mt++) {
                floatx4 acc = {0.f, 0.f, 0.f, 0.f};
                #pragma unroll
                for (int ks = 0; ks < 4; ks++)
                    acc = __builtin_amdgcn_mfma_f32_16x16x32_bf16(af2[mt][ks], bf2[ks], acc, 0, 0, 0);
                #pragma unroll
                for (int r = 0; r < 4; r++) {
                    int row = mt * 16 + quad * 4 + r;
                    ptb[row * 136 + col] = (short)f2b(gelu_fast(acc[r] + bb));
                }
            }
        }
    }
    __syncthreads();

    // phase F: big GEMM [32x128] @ [128x896], bf16 outputs
    {
        short8 af[2][4];
        #pragma unroll
        for (int mt = 0; mt < 2; mt++)
            #pragma unroll
            for (int ks = 0; ks < 4; ks++)
                af[mt][ks] = *(const short8*)(ptb + (mt * 16 + c16) * 136 + ks * 32 + quad * 8);
        for (int i = 0; i < 14; i++) {
            int nt = w + i * 4;
            short8 bf[4];
            #pragma unroll
            for (int ks = 0; ks < 4; ks++)
                bf[ks] = *(const short8*)(Wfrag + ((nt * 4 + ks) * 64 + lane) * 8);
            floatx4 acc[2];
            #pragma unroll
            for (int mt = 0; mt < 2; mt++) {
                acc[mt] = (floatx4){0.f, 0.f, 0.f, 0.f};
                #pragma unroll
                for (int ks = 0; ks < 4; ks++)
                    acc[mt] = __builtin_amdgcn_mfma_f32_16x16x32_bf16(af[mt][ks], bf[ks], acc[mt], 0, 0, 0);
            }
            int n = nt * 16 + c16;
            if (nt < 16) {
                float bb = bk[n];
                #pragma unroll
                for (int mt = 0; mt < 2; mt++)
                    #pragma unroll
                    for (int r = 0; r < 4; r++) {
                        int row = mt * 16 + quad * 4 + r;
                        kb[(size_t)(bn0 + row) * HID + n] = f2b(acc[mt][r] + bb);
                    }
            } else if (nt < 32) {
                int j = n - 256;
                float bb = bv[j];
                #pragma unroll
                for (int mt = 0; mt < 2; mt++)
                    #pragma unroll
                    for (int r = 0; r < 4; r++) {
                        int row = mt * 16 + quad * 4 + r;
                        vb[(size_t)(bn0 + row) * HID + j] = f2b(acc[mt][r] + bb);
                    }
            } else if (nt < 48) {
                int j = n - 512;
                float wr0 = rw1[384 * HID + j], wr1 = rw1[385 * HID + j];
                #pragma unroll
                for (int mt = 0; mt < 2; mt++)
                    #pragma unroll
                    for (int r = 0; r < 4; r++) {
                        int row = mt * 16 + quad * 4 + r;
                        P1[(size_t)(bn0 + row) * HID + j] =
                            f2b(acc[mt][r] + rxyS[row * 2] * wr0 + rxyS[row * 2 + 1] * wr1);
                    }
            } else {
                int j = n - 768;
                #pragma unroll
                for (int mt = 0; mt < 2; mt++)
                    #pragma unroll
                    for (int r = 0; r < 4; r++) {
                        int row = mt * 16 + quad * 4 + r;
                        P2[(size_t)(bn0 + row) * PD + j] = f2b(acc[mt][r]);
                    }
            }
        }
    }
}

// ---------------- attention: QK with q-in-registers, bf16 K/V ----------------
__global__ __launch_bounds__(256) void k_att(
    const float* __restrict__ qbuf, const ushort_t* __restrict__ kb, const ushort_t* __restrict__ vbuf,
    float* __restrict__ pm, float* __restrict__ pl, float* __restrict__ po)
{
    __shared__ float sc[8][CH2];
    __shared__ float pos[8][8][DH];
    int tid = threadIdx.x;
    int bidx = blockIdx.x;
    int c = bidx & (NC2 - 1);
    int head = (bidx >> 4) & 7;
    int b = bidx >> 7;
    const float scale = 0.17677669529663688110f;
    {
        int qq = tid >> 5, ln = tid & 31;
        float qr[DH];
        const float* qp = qbuf + (size_t)(b * HORQ + qq) * HID + head * DH;
        #pragma unroll
        for (int u = 0; u < 8; u++) {
            float4 f = *(const float4*)(qp + u * 4);
            qr[u * 4] = f.x; qr[u * 4 + 1] = f.y; qr[u * 4 + 2] = f.z; qr[u * 4 + 3] = f.w;
        }
        #pragma unroll
        for (int i = 0; i < 8; i++) {
            int nn = ln + 32 * i;
            const ushort_t* kp = kb + (size_t)(b * NN + c * CH2 + nn) * HID + head * DH;
            float s = 0.f;
            #pragma unroll
            for (int u = 0; u < 4; u++) {
                uint4 q = *(const uint4*)(kp + u * 8);
                unsigned wd[4] = {q.x, q.y, q.z, q.w};
                #pragma unroll
                for (int t2 = 0; t2 < 4; t2++) {
                    s += qr[u * 8 + 2 * t2]     * b2f(wd[t2] << 16);
                    s += qr[u * 8 + 2 * t2 + 1] * b2f(wd[t2] & 0xffff0000u);
                }
            }
            sc[qq][nn] = s * scale;
        }
    }
    __syncthreads();
    int qq = tid >> 5, r = tid & 31;
    float mx = -1e30f;
    #pragma unroll
    for (int nn = r; nn < CH2; nn += 32) mx = fmaxf(mx, sc[qq][nn]);
    #pragma unroll
    for (int m = 16; m; m >>= 1) mx = fmaxf(mx, __shfl_xor(mx, m, 32));
    float sum = 0.f;
    #pragma unroll
    for (int nn = r; nn < CH2; nn += 32) { float e = __expf(sc[qq][nn] - mx); sc[qq][nn] = e; sum += e; }
    #pragma unroll
    for (int m = 16; m; m >>= 1) sum += __shfl_xor(sum, m, 32);
    if (r == 0) { pm[bidx * 8 + qq] = mx; pl[bidx * 8 + qq] = sum; }
    __syncthreads();
    {
        int g = tid >> 5, d = tid & 31;
        float oacc[8];
        #pragma unroll
        for (int q2 = 0; q2 < 8; q2++) oacc[q2] = 0.f;
        const ushort_t* vp = vbuf + ((size_t)(b * NN + c * CH2 + g * 32)) * HID + head * DH + d;
        for (int i = 0; i < 32; i++) {
            float v = b2f(((unsigned)vp[(size_t)i * HID]) << 16);
            int nn = g * 32 + i;
            #pragma unroll
            for (int q2 = 0; q2 < 8; q2++) oacc[q2] += sc[q2][nn] * v;
        }
        #pragma unroll
        for (int q2 = 0; q2 < 8; q2++) pos[g][q2][d] = oacc[q2];
    }
    __syncthreads();
    {
        int q2 = tid >> 5, d = tid & 31;
        float o = 0.f;
        #pragma unroll
        for (int gg = 0; gg < 8; gg++) o += pos[gg][q2][d];
        po[(size_t)(bidx * 8 + q2) * DH + d] = o;
    }
}

// ---------------- merged: combine chunks + future + row heads ----------------
__global__ __launch_bounds__(256) void k_attfut(
    const float* __restrict__ pm, const float* __restrict__ pl, const float* __restrict__ po,
    const float* __restrict__ opw, const float* __restrict__ opb,
    const float* __restrict__ rw1, const float* __restrict__ rb1,
    const float* __restrict__ vw1, const float* __restrict__ vb1,
    const float* __restrict__ shw, const float* __restrict__ shb,
    const float* __restrict__ ahw, const float* __restrict__ ahb,
    float* __restrict__ F1, float* __restrict__ F2, float* __restrict__ dl, float* __restrict__ sem)
{
    __shared__ float orow[HID], fut[HID];
    int tid = threadIdx.x;
    int b = blockIdx.x >> 3, qq = blockIdx.x & 7;
    {
        int head = tid >> 5, d = tid & 31;
        int base = b * 1024 + head * 128 + qq;
        float M = -1e30f;
        #pragma unroll
        for (int c = 0; c < NC2; c++) M = fmaxf(M, pm[base + c * 8]);
        float L = 0.f, o = 0.f;
        #pragma unroll
        for (int c = 0; c < NC2; c++) {
            float wgt = __expf(pm[base + c * 8] - M);
            L += wgt * pl[base + c * 8];
            o += wgt * po[(size_t)(base + c * 8) * DH + d];
        }
        orow[head * DH + d] = o / L;
    }
    __syncthreads();
    {
        float a0 = opb[tid], a1 = 0.f, a2 = 0.f, a3 = 0.f;
        for (int i = 0; i < HID; i += 4) {
            a0 += orow[i] * opw[i * HID + tid];
            a1 += orow[i + 1] * opw[(i + 1) * HID + tid];
            a2 += orow[i + 2] * opw[(i + 2) * HID + tid];
            a3 += orow[i + 3] * opw[(i + 3) * HID + tid];
        }
        fut[tid] = a0 + a1 + a2 + a3;
    }
    __syncthreads();
    int bh = b * HORQ + qq;
    {
        float a0 = rb1[tid], a1 = 0.f, a2 = 0.f, a3 = 0.f;
        for (int i = 0; i < HID; i += 4) {
            a0 += fut[i] * rw1[i * HID + tid];
            a1 += fut[i + 1] * rw1[(i + 1) * HID + tid];
            a2 += fut[i + 2] * rw1[(i + 2) * HID + tid];
            a3 += fut[i + 3] * rw1[(i + 3) * HID + tid];
        }
        F1[(size_t)bh * HID + tid] = a0 + a1 + a2 + a3;
    }
    if (tid < PD) {
        float a0 = vb1[tid], a1 = 0.f, a2 = 0.f, a3 = 0.f;
        for (int i = 0; i < HID; i += 4) {
            a0 += fut[i] * vw1[i * PD + tid];
            a1 += fut[i + 1] * vw1[(i + 1) * PD + tid];
            a2 += fut[i + 2] * vw1[(i + 2) * PD + tid];
            a3 += fut[i + 3] * vw1[(i + 3) * PD + tid];
        }
        F2[(size_t)bh * PD + tid] = a0 + a1 + a2 + a3;
    }
    {
        int j = tid >> 3, part = tid & 7;
        float s3 = 0.f;
        for (int i = part * 32; i < part * 32 + 32; i++) s3 += fut[i] * shw[i * 32 + j];
        s3 += __shfl_xor(s3, 1);
        s3 += __shfl_xor(s3, 2);
        s3 += __shfl_xor(s3, 4);
        if (part == 0) sem[bh * 32 + j] = s3 + shb[j];
    }
    if (tid < 128) {
        int j = tid >> 6, part = tid & 63;
        float a = 0.f;
        #pragma unroll
        for (int u = 0; u < 4; u++) { int i = part * 4 + u; a += fut[i] * ahw[i * 2 + j]; }
        #pragma unroll
        for (int m = 32; m; m >>= 1) a += __shfl_xor(a, m);
        if (part == 0) dl[bh * 2 + j] = 0.1f * tanhf(a + ahb[j]);
    }
}

// ---------------- anchor cumsum ----------------
__global__ void k_cum(const float* __restrict__ aobs, const float* __restrict__ dl, float* __restrict__ out0)
{
    int tid = threadIdx.x;
    if (tid < 16) {
        int b = tid >> 1, c = tid & 1;
        float acc = aobs[(b * TT + 7) * 2 + c];
        for (int h = 0; h < HORQ; h++) {
            acc += dl[(b * HORQ + h) * 2 + c];
            out0[(b * HORQ + h) * 2 + c] = acc;
        }
    }
}

// ---------------- final epilogue: chunk-outer / h-inner, 16 lanes per point ----------
// Weights + P-slices loaded ONCE per thread (structurally - h loop is inside).
// Persistent state = 24 accumulator regs (s0/s1/sv per h).
__global__ __launch_bounds__(256) void k_fin(
    const float* __restrict__ F1, const float* __restrict__ F2,
    const ushort_t* __restrict__ P1, const ushort_t* __restrict__ P2,
    const float* __restrict__ rw2, const float* __restrict__ rb2,
    const float* __restrict__ vw2, const float* __restrict__ vb2,
    const float* __restrict__ ap,
    float* __restrict__ out1, float* __restrict__ out2)
{
    int tid = threadIdx.x;
    int g = tid >> 4;     // point group (0..15)
    int l = tid & 15;
    int bn = blockIdx.x * 16 + g;
    int b = bn >> 12;     // block-uniform
    int bh0 = b * HORQ;

    float s0[8], s1[8], sv[8];
    #pragma unroll
    for (int h = 0; h < 8; h++) { s0[h] = 0.f; s1[h] = 0.f; sv[h] = 0.f; }

    // rh: lane owns j = l*16 .. l*16+15, in 4 chunks of 4
    {
        const ushort_t* p1base = P1 + (size_t)bn * HID + l * 16;
        const float* f1base = F1 + (size_t)bh0 * HID + l * 16;
        #pragma unroll
        for (int c = 0; c < 4; c++) {
            uint2 pq = *(const uint2*)(p1base + c * 4);
            float p0 = b2f(pq.x << 16), p1v = b2f(pq.x & 0xffff0000u);
            float p2 = b2f(pq.y << 16), p3 = b2f(pq.y & 0xffff0000u);
            const float* rwp = rw2 + (l * 16 + c * 4) * 2;
            float4 ra = *(const float4*)rwp;        // w0[j0],w1[j0],w0[j0+1],w1[j0+1]
            float4 rb = *(const float4*)(rwp + 4);  // j0+2, j0+3
            #pragma unroll
            for (int h = 0; h < 8; h++) {
                float4 f = *(const float4*)(f1base + h * HID + c * 4);
                float g0 = gelu_sig(f.x + p0);
                float g1 = gelu_sig(f.y + p1v);
                float g2 = gelu_sig(f.z + p2);
                float g3 = gelu_sig(f.w + p3);
                s0[h] += g0 * ra.x + g1 * ra.z + g2 * rb.x + g3 * rb.z;
                s1[h] += g0 * ra.y + g1 * ra.w + g2 * rb.y + g3 * rb.w;
            }
        }
    }
    // vh: lane owns j = l*8 .. l*8+7, in 2 chunks of 4
    {
        const ushort_t* p2base = P2 + (size_t)bn * PD + l * 8;
        const float* f2base = F2 + (size_t)bh0 * PD + l * 8;
        #pragma unroll
        for (int c = 0; c < 2; c++) {
            uint2 pq = *(const uint2*)(p2base + c * 4);
            float p0 = b2f(pq.x << 16), p1v = b2f(pq.x & 0xffff0000u);
            float p2 = b2f(pq.y << 16), p3 = b2f(pq.y & 0xffff0000u);
            float4 wv4 = *(const float4*)(vw2 + l * 8 + c * 4);
            #pragma unroll
            for (int h = 0; h < 8; h++) {
                float4 f = *(const float4*)(f2base + h * PD + c * 4);
                sv[h] += gelu_sig(f.x + p0) * wv4.x
                       + gelu_sig(f.y + p1v) * wv4.y
                       + gelu_sig(f.z + p2) * wv4.z
                       + gelu_sig(f.w + p3) * wv4.w;
            }
        }
    }

    float rb20 = rb2[0], rb21 = rb2[1], vb20 = vb2[0];
    #pragma unroll
    for (int h = 0; h < 8; h++) {
        float a0 = s0[h], a1 = s1[h], a2 = sv[h];
        #pragma unroll
        for (int m = 8; m; m >>= 1) {
            a0 += __shfl_xor(a0, m, 16);
            a1 += __shfl_xor(a1, m, 16);
            a2 += __shfl_xor(a2, m, 16);
        }
        if (l == 0) {
            float rx = 0.1f * tanh_fast(a0 + rb20);
            float ry = 0.1f * tanh_fast(a1 + rb21);
            int bh = bh0 + h;
            out1[((size_t)bn * HORQ + h) * 2 + 0] = ap[bh * 2 + 0] + rx;
            out1[((size_t)bn * HORQ + h) * 2 + 1] = ap[bh * 2 + 1] + ry;
            out2[(size_t)bn * HORQ + h] = a2 + vb20;
        }
    }
}

extern "C" void kernel_launch(void* const* d_in, const int* in_sizes, int n_in,
                              void* d_out, int out_size, void* d_ws, size_t ws_size,
                              hipStream_t stream)
{
    const float* obs  = (const float*)d_in[0];
    const int*   vis  = (const int*)d_in[1];
    const float* rel  = (const float*)d_in[2];
    const float* aobs = (const float*)d_in[3];
    const float* avel = (const float*)d_in[4];
    const float* lnw = (const float*)d_in[6];
    const float* lnb = (const float*)d_in[7];
    const float* ew1 = (const float*)d_in[8];
    const float* eb1 = (const float*)d_in[9];
    const float* ew2 = (const float*)d_in[10];
    const float* eb2 = (const float*)d_in[11];
    const float* te  = (const float*)d_in[12];
    const float* aw  = (const float*)d_in[13];
    const float* ab  = (const float*)d_in[14];
    const float* qw  = (const float*)d_in[15];
    const float* qbias = (const float*)d_in[16];
    const float* ipw = (const float*)d_in[17];
    const float* ipb = (const float*)d_in[18];
    const float* opw = (const float*)d_in[19];
    const float* opb = (const float*)d_in[20];
    const float* ahw = (const float*)d_in[21];
    const float* ahb = (const float*)d_in[22];
    const float* rw1 = (const float*)d_in[23];
    const float* rb1 = (const float*)d_in[24];
    const float* rw2 = (const float*)d_in[25];
    const float* rb2 = (const float*)d_in[26];
    const float* vw1 = (const float*)d_in[27];
    const float* vb1 = (const float*)d_in[28];
    const float* vw2 = (const float*)d_in[29];
    const float* vb2 = (const float*)d_in[30];
    const float* shw = (const float*)d_in[31];
    const float* shb = (const float*)d_in[32];

    float* W = (float*)d_ws;
    size_t o = 0;
    float* Wk  = W + o; o += (size_t)PD * HID;
    float* Wv  = W + o; o += (size_t)PD * HID;
    float* bk  = W + o; o += HID;
    float* bv  = W + o; o += HID;
    float* qb_ = W + o; o += (size_t)BB * HORQ * HID;
    float* F1  = W + o; o += (size_t)BB * HORQ * HID;
    float* F2  = W + o; o += (size_t)BB * HORQ * PD;
    float* dl  = W + o; o += (size_t)BB * HORQ * 2;
    float* pm  = W + o; o += (size_t)BB * NHD * NC2 * 8;
    float* pl  = W + o; o += (size_t)BB * NHD * NC2 * 8;
    float* po  = W + o; o += (size_t)BB * NHD * NC2 * 8 * DH;
    ushort_t* kb   = (ushort_t*)(W + o); o += (size_t)BB * NN * HID / 2;
    ushort_t* vbuf = (ushort_t*)(W + o); o += (size_t)BB * NN * HID / 2;
    ushort_t* P1   = (ushort_t*)(W + o); o += (size_t)BB * NN * HID / 2;
    ushort_t* P2   = (ushort_t*)(W + o); o += (size_t)BB * NN * PD / 2;
    short* Sf = (short*)(W + o);
    short* Wfrag  = Sf;
    short* w1frag = Sf + 114688;
    short* w2frag = Sf + 114688 + 8192;

    float* out0 = (float*)d_out;
    float* out1 = out0 + BB * HORQ * 2;
    float* out2 = out1 + (size_t)BB * NN * HORQ * 2;
    float* out3 = out2 + (size_t)BB * NN * HORQ;

    k_fuse<<<PD + 1, 256, 0, stream>>>(qw, qbias, ipw, ipb, Wk, Wv, bk, bv);
    k_prep<<<72 + 64, 256, 0, stream>>>(Wk, Wv, rw1, vw1, ew1, ew2,
                                        aobs, avel, te, aw, ab, ipw, ipb,
                                        Wfrag, w1frag, w2frag, qb_);
    k_main<<<BB * NN / 32, 256, 0, stream>>>(obs, vis, rel, lnw, lnb, eb1, eb2,
                                             Wfrag, w1frag, w2frag, bk, bv, rw1,
                                             kb, vbuf, P1, P2);
    k_att<<<BB * NHD * NC2, 256, 0, stream>>>(qb_, kb, vbuf, pm, pl, po);
    k_attfut<<<BB * HORQ, 256, 0, stream>>>(pm, pl, po, opw, opb, rw1, rb1, vw1, vb1,
                                            shw, shb, ahw, ahb, F1, F2, dl, out3);
    k_cum<<<1, 64, 0, stream>>>(aobs, dl, out0);
    k_fin<<<BB * NN / 16, 256, 0, stream>>>(F1, F2, P1, P2, rw2, rb2, vw2, vb2,
                                            out0, out1, out2);
}

// Round 12
// 252.666 us; speedup vs baseline: 1.0442x; 1.0427x over previous
//
#include <hip/hip_runtime.h>
#include <math.h>

#define BB 8
#define NN 4096
#define TT 8
#define HORQ 8
#define PD 128
#define HID 256
#define NHD 8
#define DH 32
#define FE 56
#define NC2 16
#define CH2 256

typedef __attribute__((ext_vector_type(8))) short short8;
typedef __attribute__((ext_vector_type(4))) float floatx4;
typedef __attribute__((ext_vector_type(2))) float floatx2;
typedef unsigned short ushort_t;

// gelu via tanh-form, exp-based (encoder path)
__device__ __forceinline__ float gelu_fast(float x) {
    float x2 = x * x;
    float y2 = x * fmaf(0.0713551f, x2, 1.5957691f);
    float e = __expf(y2);
    return x - x * __builtin_amdgcn_rcpf(1.f + e);
}

// cheaper gelu for k_fin epilogue: x * sigmoid(1.702x)
__device__ __forceinline__ float gelu_sig(float x) {
    float e = __expf(-1.702f * x);
    return x * __builtin_amdgcn_rcpf(1.f + e);
}

__device__ __forceinline__ float tanh_fast(float x) {
    float e = __expf(2.f * x);
    return 1.f - 2.f * __builtin_amdgcn_rcpf(1.f + e);
}

// fp32 -> bf16 round-to-nearest-even
__device__ __forceinline__ ushort_t f2b(float x) {
    union { float f; unsigned u; } c; c.f = x;
    unsigned r = c.u + 0x7fffu + ((c.u >> 16) & 1u);
    return (ushort_t)(r >> 16);
}
__device__ __forceinline__ float b2f(unsigned hi) {
    union { unsigned u; float f; } c; c.u = hi;
    return c.f;
}

// ---------------- fuse query_w into k/v projections (fp32, 4-acc chains) ----------------
__global__ __launch_bounds__(256) void k_fuse(
    const float* __restrict__ qw, const float* __restrict__ qb,
    const float* __restrict__ ipw, const float* __restrict__ ipb,
    float* __restrict__ Wk, float* __restrict__ Wv,
    float* __restrict__ bk, float* __restrict__ bv)
{
    int j = threadIdx.x;
    int blk = blockIdx.x;
    const float* src = (blk < PD) ? (qw + blk * HID) : qb;
    float sk0 = 0.f, sk1 = 0.f, sk2 = 0.f, sk3 = 0.f;
    float sv0 = 0.f, sv1 = 0.f, sv2 = 0.f, sv3 = 0.f;
    for (int l = 0; l < HID; l += 4) {
        float w0 = src[l], w1 = src[l + 1], w2 = src[l + 2], w3 = src[l + 3];
        sk0 += w0 * ipw[l * 768 + 256 + j];
        sk1 += w1 * ipw[(l + 1) * 768 + 256 + j];
        sk2 += w2 * ipw[(l + 2) * 768 + 256 + j];
        sk3 += w3 * ipw[(l + 3) * 768 + 256 + j];
        sv0 += w0 * ipw[l * 768 + 512 + j];
        sv1 += w1 * ipw[(l + 1) * 768 + 512 + j];
        sv2 += w2 * ipw[(l + 2) * 768 + 512 + j];
        sv3 += w3 * ipw[(l + 3) * 768 + 512 + j];
    }
    float sk = sk0 + sk1 + sk2 + sk3, sv = sv0 + sv1 + sv2 + sv3;
    if (blk < PD) {
        Wk[blk * HID + j] = sk;
        Wv[blk * HID + j] = sv;
    } else {
        bk[j] = sk + ipb[256 + j];
        bv[j] = sv + ipb[512 + j];
    }
}

// ---------------- pack weight fragments + tq/q rows ----------------
__global__ __launch_bounds__(256) void k_prep(
    const float* __restrict__ Wk, const float* __restrict__ Wv,
    const float* __restrict__ rw1, const float* __restrict__ vw1,
    const float* __restrict__ w1, const float* __restrict__ w2,
    const float* __restrict__ aobs, const float* __restrict__ avel,
    const float* __restrict__ te, const float* __restrict__ aw, const float* __restrict__ ab,
    const float* __restrict__ ipw, const float* __restrict__ ipb,
    short* __restrict__ Wfrag, short* __restrict__ w1frag, short* __restrict__ w2frag,
    float* __restrict__ qb_)
{
    __shared__ float af[32];
    __shared__ float tqs[HID];
    int tid = threadIdx.x;
    int blk = blockIdx.x;
    int ks = tid >> 6, lane = tid & 63;
    int quad = lane >> 4, c16 = lane & 15;
    if (blk < 56) {
        int nt = blk;
        int n = nt * 16 + c16;
        for (int j = 0; j < 8; j++) {
            int k = ks * 32 + quad * 8 + j;
            float v;
            if (n < 256)      v = Wk[k * HID + n];
            else if (n < 512) v = Wv[k * HID + (n - 256)];
            else if (n < 768) v = rw1[(256 + k) * HID + (n - 512)];
            else              v = vw1[(256 + k) * PD + (n - 768)];
            Wfrag[((nt * 4 + ks) * 64 + lane) * 8 + j] = (short)f2b(v);
        }
    } else if (blk < 64) {
        if (ks < 2) {
            int nt = blk - 56;
            int n = nt * 16 + c16;
            for (int j = 0; j < 8; j++) {
                int k = ks * 32 + quad * 8 + j;
                float v = (k < FE) ? w1[k * PD + n] : 0.f;
                w1frag[((nt * 2 + ks) * 64 + lane) * 8 + j] = (short)f2b(v);
            }
        }
    } else if (blk < 72) {
        int nt = blk - 64;
        int n = nt * 16 + c16;
        for (int j = 0; j < 8; j++) {
            int k = ks * 32 + quad * 8 + j;
            w2frag[((nt * 4 + ks) * 64 + lane) * 8 + j] = (short)f2b(w2[k * PD + n]);
        }
    } else {
        int bh = blk - 72;
        int b = bh >> 3, h = bh & 7;
        if (tid < 32) {
            int t = tid >> 2, m = tid & 3;
            af[tid] = (m < 2) ? aobs[(b * TT + t) * 2 + m] : avel[(b * TT + t) * 2 + (m - 2)];
        }
        __syncthreads();
        float s = te[h * HID + tid] + ab[tid];
        for (int i = 0; i < 32; i++) s += af[i] * aw[i * HID + tid];
        tqs[tid] = s;
        __syncthreads();
        float q0 = ipb[tid], q1 = 0.f, q2 = 0.f, q3 = 0.f;
        for (int i = 0; i < HID; i += 4) {
            q0 += tqs[i] * ipw[i * 768 + tid];
            q1 += tqs[i + 1] * ipw[(i + 1) * 768 + tid];
            q2 += tqs[i + 2] * ipw[(i + 2) * 768 + tid];
            q3 += tqs[i + 3] * ipw[(i + 3) * 768 + tid];
        }
        qb_[(size_t)bh * HID + tid] = q0 + q1 + q2 + q3;
    }
}

// ---------------- fused encoder + projections via bf16 MFMA (32-point tiles) -------
#define U1_OFF 0
#define XNB_OFF 8704
#define PTB_OFF 13312
#define RXY_OFF 22016
#define MU_OFF 22272
#define RS_OFF 22400
#define SMEM_BYTES 22528

__global__ __launch_bounds__(256) void k_main(
    const float* __restrict__ obs, const int* __restrict__ vis,
    const float* __restrict__ rel,
    const float* __restrict__ lnw, const float* __restrict__ lnb,
    const float* __restrict__ b1, const float* __restrict__ b2,
    const short* __restrict__ Wfrag, const short* __restrict__ w1frag,
    const short* __restrict__ w2frag,
    const float* __restrict__ bk, const float* __restrict__ bv,
    const float* __restrict__ rw1,
    ushort_t* __restrict__ kb, ushort_t* __restrict__ vb,
    ushort_t* __restrict__ P1, ushort_t* __restrict__ P2)
{
    __shared__ __align__(16) char smem[SMEM_BYTES];
    float* xnf = (float*)(smem + U1_OFF);       // [32][57]
    short* h1b = (short*)(smem + U1_OFF);       // [32][136]
    short* xnb = (short*)(smem + XNB_OFF);      // [32][72]
    short* ptb = (short*)(smem + PTB_OFF);      // [32][136]
    float* rxyS = (float*)(smem + RXY_OFF);     // [32][2]
    float* muS = (float*)(smem + MU_OFF);       // [32]
    float* rsS = (float*)(smem + RS_OFF);       // [32]

    int tid = threadIdx.x;
    int w = tid >> 6, lane = tid & 63;
    int quad = lane >> 4, c16 = lane & 15;
    int bn0 = blockIdx.x * 32;

    // phase A: one (p,t) pair per thread, branchless
    {
        int p = tid >> 3, t = tid & 7;
        int bn = bn0 + p;
        float2 oc = *(const float2*)(obs + (bn * TT + t) * 2);
        int tp = t ? (t - 1) : 0;
        float2 op = *(const float2*)(obs + (bn * TT + tp) * 2);
        float dx = t ? (oc.x - op.x) : 0.f;
        float dy = t ? (oc.y - op.y) : 0.f;
        float vv = (float)vis[bn * TT + t];
        float2 rl = *(const float2*)(rel + bn * 2);
        float* xp = xnf + p * 57 + t * 7;
        xp[0] = oc.x; xp[1] = oc.y; xp[2] = dx; xp[3] = dy;
        xp[4] = vv; xp[5] = rl.x; xp[6] = rl.y;
    }
    if (tid < 64) rxyS[tid] = rel[bn0 * 2 + tid];
    __syncthreads();

    // phase B: LN stats, 8 lanes per point
    {
        int p = tid >> 3, r = tid & 7;
        float s = 0.f, ss = 0.f;
        for (int e = r; e < FE; e += 8) { float v = xnf[p * 57 + e]; s += v; ss += v * v; }
        s += __shfl_xor(s, 1); ss += __shfl_xor(ss, 1);
        s += __shfl_xor(s, 2); ss += __shfl_xor(ss, 2);
        s += __shfl_xor(s, 4); ss += __shfl_xor(ss, 4);
        if (r == 0) {
            float mu = s * (1.f / FE);
            float var = ss * (1.f / FE) - mu * mu;
            muS[p] = mu;
            rsS[p] = rsqrtf(var + 1e-5f);
        }
    }
    __syncthreads();

    // phase C: normalize -> bf16 A-layout (rows padded to 72)
    for (int idx = tid; idx < 32 * 64; idx += 256) {
        int p = idx >> 6, e = idx & 63;
        float v = 0.f;
        if (e < FE) v = (xnf[p * 57 + e] - muS[p]) * rsS[p] * lnw[e] + lnb[e];
        xnb[p * 72 + e] = (short)f2b(v);
    }
    __syncthreads();

    // phase D: enc1 (2 m-tiles)
    {
        short8 af1[2][2];
        #pragma unroll
        for (int mt = 0; mt < 2; mt++)
            #pragma unroll
            for (int ks = 0; ks < 2; ks++)
                af1[mt][ks] = *(const short8*)(xnb + (mt * 16 + c16) * 72 + ks * 32 + quad * 8);
        #pragma unroll
        for (int ntl = 0; ntl < 2; ntl++) {
            int nt = w * 2 + ntl;
            short8 bf1[2];
            #pragma unroll
            for (int ks = 0; ks < 2; ks++)
                bf1[ks] = *(const short8*)(w1frag + ((nt * 2 + ks) * 64 + lane) * 8);
            int col = nt * 16 + c16;
            float bb = b1[col];
            #pragma unroll
            for (int mt = 0; mt < 2; mt++) {
                floatx4 acc = {0.f, 0.f, 0.f, 0.f};
                acc = __builtin_amdgcn_mfma_f32_16x16x32_bf16(af1[mt][0], bf1[0], acc, 0, 0, 0);
                acc = __builtin_amdgcn_mfma_f32_16x16x32_bf16(af1[mt][1], bf1[1], acc, 0, 0, 0);
                #pragma unroll
                for (int r = 0; r < 4; r++) {
                    int row = mt * 16 + quad * 4 + r;
                    h1b[row * 136 + col] = (short)f2b(gelu_fast(acc[r] + bb));
                }
            }
        }
    }
    __syncthreads();

    // phase E: enc2
    {
        short8 af2[2][4];
        #pragma unroll
        for (int mt = 0; mt < 2; mt++)
            #pragma unroll
            for (int ks = 0; ks < 4; ks++)
                af2[mt][ks] = *(const short8*)(h1b + (mt * 16 + c16) * 136 + ks * 32 + quad * 8);
        #pragma unroll
        for (int ntl = 0; ntl < 2; ntl++) {
            int nt = w * 2 + ntl;
            short8 bf2[4];
            #pragma unroll
            for (int ks = 0; ks < 4; ks++)
                bf2[ks] = *(const short8*)(w2frag + ((nt * 4 + ks) * 64 + lane) * 8);
            int col = nt * 16 + c16;
            float bb = b2[col];
            #pragma unroll
            for (int mt = 0; mt < 2; mt++) {
                floatx4 acc = {0.f, 0.f, 0.f, 0.f};
                #pragma unroll
                for (int ks = 0; ks < 4; ks++)
                    acc = __builtin_amdgcn_mfma_f32_16x16x32_bf16(af2[mt][ks], bf2[ks], acc, 0, 0, 0);
                #pragma unroll
                for (int r = 0; r < 4; r++) {
                    int row = mt * 16 + quad * 4 + r;
                    ptb[row * 136 + col] = (short)f2b(gelu_fast(acc[r] + bb));
                }
            }
        }
    }
    __syncthreads();

    // phase F: big GEMM [32x128] @ [128x896], bf16 outputs
    {
        short8 af[2][4];
        #pragma unroll
        for (int mt = 0; mt < 2; mt++)
            #pragma unroll
            for (int ks = 0; ks < 4; ks++)
                af[mt][ks] = *(const short8*)(ptb + (mt * 16 + c16) * 136 + ks * 32 + quad * 8);
        for (int i = 0; i < 14; i++) {
            int nt = w + i * 4;
            short8 bf[4];
            #pragma unroll
            for (int ks = 0; ks < 4; ks++)
                bf[ks] = *(const short8*)(Wfrag + ((nt * 4 + ks) * 64 + lane) * 8);
            floatx4 acc[2];
            #pragma unroll
            for (int mt = 0; mt < 2; mt++) {
                acc[mt] = (floatx4){0.f, 0.f, 0.f, 0.f};
                #pragma unroll
                for (int ks = 0; ks < 4; ks++)
                    acc[mt] = __builtin_amdgcn_mfma_f32_16x16x32_bf16(af[mt][ks], bf[ks], acc[mt], 0, 0, 0);
            }
            int n = nt * 16 + c16;
            if (nt < 16) {
                float bb = bk[n];
                #pragma unroll
                for (int mt = 0; mt < 2; mt++)
                    #pragma unroll
                    for (int r = 0; r < 4; r++) {
                        int row = mt * 16 + quad * 4 + r;
                        kb[(size_t)(bn0 + row) * HID + n] = f2b(acc[mt][r] + bb);
                    }
            } else if (nt < 32) {
                int j = n - 256;
                float bb = bv[j];
                #pragma unroll
                for (int mt = 0; mt < 2; mt++)
                    #pragma unroll
                    for (int r = 0; r < 4; r++) {
                        int row = mt * 16 + quad * 4 + r;
                        vb[(size_t)(bn0 + row) * HID + j] = f2b(acc[mt][r] + bb);
                    }
            } else if (nt < 48) {
                int j = n - 512;
                float wr0 = rw1[384 * HID + j], wr1 = rw1[385 * HID + j];
                #pragma unroll
                for (int mt = 0; mt < 2; mt++)
                    #pragma unroll
                    for (int r = 0; r < 4; r++) {
                        int row = mt * 16 + quad * 4 + r;
                        P1[(size_t)(bn0 + row) * HID + j] =
                            f2b(acc[mt][r] + rxyS[row * 2] * wr0 + rxyS[row * 2 + 1] * wr1);
                    }
            } else {
                int j = n - 768;
                #pragma unroll
                for (int mt = 0; mt < 2; mt++)
                    #pragma unroll
                    for (int r = 0; r < 4; r++) {
                        int row = mt * 16 + quad * 4 + r;
                        P2[(size_t)(bn0 + row) * PD + j] = f2b(acc[mt][r]);
                    }
            }
        }
    }
}

// ---------------- attention: QK with q-in-registers, bf16 K/V ----------------
__global__ __launch_bounds__(256) void k_att(
    const float* __restrict__ qbuf, const ushort_t* __restrict__ kb, const ushort_t* __restrict__ vbuf,
    float* __restrict__ pm, float* __restrict__ pl, float* __restrict__ po)
{
    __shared__ float sc[8][CH2];
    __shared__ float pos[8][8][DH];
    int tid = threadIdx.x;
    int bidx = blockIdx.x;
    int c = bidx & (NC2 - 1);
    int head = (bidx >> 4) & 7;
    int b = bidx >> 7;
    const float scale = 0.17677669529663688110f;
    {
        int qq = tid >> 5, ln = tid & 31;
        float qr[DH];
        const float* qp = qbuf + (size_t)(b * HORQ + qq) * HID + head * DH;
        #pragma unroll
        for (int u = 0; u < 8; u++) {
            float4 f = *(const float4*)(qp + u * 4);
            qr[u * 4] = f.x; qr[u * 4 + 1] = f.y; qr[u * 4 + 2] = f.z; qr[u * 4 + 3] = f.w;
        }
        #pragma unroll
        for (int i = 0; i < 8; i++) {
            int nn = ln + 32 * i;
            const ushort_t* kp = kb + (size_t)(b * NN + c * CH2 + nn) * HID + head * DH;
            float s = 0.f;
            #pragma unroll
            for (int u = 0; u < 4; u++) {
                uint4 q = *(const uint4*)(kp + u * 8);
                unsigned wd[4] = {q.x, q.y, q.z, q.w};
                #pragma unroll
                for (int t2 = 0; t2 < 4; t2++) {
                    s += qr[u * 8 + 2 * t2]     * b2f(wd[t2] << 16);
                    s += qr[u * 8 + 2 * t2 + 1] * b2f(wd[t2] & 0xffff0000u);
                }
            }
            sc[qq][nn] = s * scale;
        }
    }
    __syncthreads();
    int qq = tid >> 5, r = tid & 31;
    float mx = -1e30f;
    #pragma unroll
    for (int nn = r; nn < CH2; nn += 32) mx = fmaxf(mx, sc[qq][nn]);
    #pragma unroll
    for (int m = 16; m; m >>= 1) mx = fmaxf(mx, __shfl_xor(mx, m, 32));
    float sum = 0.f;
    #pragma unroll
    for (int nn = r; nn < CH2; nn += 32) { float e = __expf(sc[qq][nn] - mx); sc[qq][nn] = e; sum += e; }
    #pragma unroll
    for (int m = 16; m; m >>= 1) sum += __shfl_xor(sum, m, 32);
    if (r == 0) { pm[bidx * 8 + qq] = mx; pl[bidx * 8 + qq] = sum; }
    __syncthreads();
    {
        int g = tid >> 5, d = tid & 31;
        float oacc[8];
        #pragma unroll
        for (int q2 = 0; q2 < 8; q2++) oacc[q2] = 0.f;
        const ushort_t* vp = vbuf + ((size_t)(b * NN + c * CH2 + g * 32)) * HID + head * DH + d;
        for (int i = 0; i < 32; i++) {
            float v = b2f(((unsigned)vp[(size_t)i * HID]) << 16);
            int nn = g * 32 + i;
            #pragma unroll
            for (int q2 = 0; q2 < 8; q2++) oacc[q2] += sc[q2][nn] * v;
        }
        #pragma unroll
        for (int q2 = 0; q2 < 8; q2++) pos[g][q2][d] = oacc[q2];
    }
    __syncthreads();
    {
        int q2 = tid >> 5, d = tid & 31;
        float o = 0.f;
        #pragma unroll
        for (int gg = 0; gg < 8; gg++) o += pos[gg][q2][d];
        po[(size_t)(bidx * 8 + q2) * DH + d] = o;
    }
}

// ---------------- merged: combine chunks + future + row heads ----------------
__global__ __launch_bounds__(256) void k_attfut(
    const float* __restrict__ pm, const float* __restrict__ pl, const float* __restrict__ po,
    const float* __restrict__ opw, const float* __restrict__ opb,
    const float* __restrict__ rw1, const float* __restrict__ rb1,
    const float* __restrict__ vw1, const float* __restrict__ vb1,
    const float* __restrict__ shw, const float* __restrict__ shb,
    const float* __restrict__ ahw, const float* __restrict__ ahb,
    float* __restrict__ F1, float* __restrict__ F2, float* __restrict__ dl, float* __restrict__ sem)
{
    __shared__ float orow[HID], fut[HID];
    int tid = threadIdx.x;
    int b = blockIdx.x >> 3, qq = blockIdx.x & 7;
    {
        int head = tid >> 5, d = tid & 31;
        int base = b * 1024 + head * 128 + qq;
        float M = -1e30f;
        #pragma unroll
        for (int c = 0; c < NC2; c++) M = fmaxf(M, pm[base + c * 8]);
        float L = 0.f, o = 0.f;
        #pragma unroll
        for (int c = 0; c < NC2; c++) {
            float wgt = __expf(pm[base + c * 8] - M);
            L += wgt * pl[base + c * 8];
            o += wgt * po[(size_t)(base + c * 8) * DH + d];
        }
        orow[head * DH + d] = o / L;
    }
    __syncthreads();
    {
        float a0 = opb[tid], a1 = 0.f, a2 = 0.f, a3 = 0.f;
        for (int i = 0; i < HID; i += 4) {
            a0 += orow[i] * opw[i * HID + tid];
            a1 += orow[i + 1] * opw[(i + 1) * HID + tid];
            a2 += orow[i + 2] * opw[(i + 2) * HID + tid];
            a3 += orow[i + 3] * opw[(i + 3) * HID + tid];
        }
        fut[tid] = a0 + a1 + a2 + a3;
    }
    __syncthreads();
    int bh = b * HORQ + qq;
    {
        float a0 = rb1[tid], a1 = 0.f, a2 = 0.f, a3 = 0.f;
        for (int i = 0; i < HID; i += 4) {
            a0 += fut[i] * rw1[i * HID + tid];
            a1 += fut[i + 1] * rw1[(i + 1) * HID + tid];
            a2 += fut[i + 2] * rw1[(i + 2) * HID + tid];
            a3 += fut[i + 3] * rw1[(i + 3) * HID + tid];
        }
        F1[(size_t)bh * HID + tid] = a0 + a1 + a2 + a3;
    }
    if (tid < PD) {
        float a0 = vb1[tid], a1 = 0.f, a2 = 0.f, a3 = 0.f;
        for (int i = 0; i < HID; i += 4) {
            a0 += fut[i] * vw1[i * PD + tid];
            a1 += fut[i + 1] * vw1[(i + 1) * PD + tid];
            a2 += fut[i + 2] * vw1[(i + 2) * PD + tid];
            a3 += fut[i + 3] * vw1[(i + 3) * PD + tid];
        }
        F2[(size_t)bh * PD + tid] = a0 + a1 + a2 + a3;
    }
    {
        int j = tid >> 3, part = tid & 7;
        float s3 = 0.f;
        for (int i = part * 32; i < part * 32 + 32; i++) s3 += fut[i] * shw[i * 32 + j];
        s3 += __shfl_xor(s3, 1);
        s3 += __shfl_xor(s3, 2);
        s3 += __shfl_xor(s3, 4);
        if (part == 0) sem[bh * 32 + j] = s3 + shb[j];
    }
    if (tid < 128) {
        int j = tid >> 6, part = tid & 63;
        float a = 0.f;
        #pragma unroll
        for (int u = 0; u < 4; u++) { int i = part * 4 + u; a += fut[i] * ahw[i * 2 + j]; }
        #pragma unroll
        for (int m = 32; m; m >>= 1) a += __shfl_xor(a, m);
        if (part == 0) dl[bh * 2 + j] = 0.1f * tanhf(a + ahb[j]);
    }
}

// ---------------- anchor cumsum ----------------
__global__ void k_cum(const float* __restrict__ aobs, const float* __restrict__ dl, float* __restrict__ out0)
{
    int tid = threadIdx.x;
    if (tid < 16) {
        int b = tid >> 1, c = tid & 1;
        float acc = aobs[(b * TT + 7) * 2 + c];
        for (int h = 0; h < HORQ; h++) {
            acc += dl[(b * HORQ + h) * 2 + c];
            out0[(b * HORQ + h) * 2 + c] = acc;
        }
    }
}

// ---------------- final epilogue: 4 points per wave (16 lanes/point) — R10 measured-best ----
// Persistent per-lane state: p1f[16]+p2f[8]. Weights loaded via pointers per h.
__global__ __launch_bounds__(256) void k_fin(
    const float* __restrict__ F1, const float* __restrict__ F2,
    const ushort_t* __restrict__ P1, const ushort_t* __restrict__ P2,
    const float* __restrict__ rw2, const float* __restrict__ rb2,
    const float* __restrict__ vw2, const float* __restrict__ vb2,
    const float* __restrict__ ap,
    float* __restrict__ out1, float* __restrict__ out2)
{
    int tid = threadIdx.x;
    int g = tid >> 4;     // point group in block (0..15)
    int l = tid & 15;
    int bn = blockIdx.x * 16 + g;
    int b = bn >> 12;     // block-uniform

    // P1 slice: 16 consecutive bf16 (persistent)
    float p1f[16];
    {
        const uint4* p1p = (const uint4*)(P1 + (size_t)bn * HID + l * 16);
        #pragma unroll
        for (int c = 0; c < 2; c++) {
            uint4 q = p1p[c];
            unsigned wd[4] = {q.x, q.y, q.z, q.w};
            #pragma unroll
            for (int u = 0; u < 4; u++) {
                p1f[c * 8 + 2 * u]     = b2f(wd[u] << 16);
                p1f[c * 8 + 2 * u + 1] = b2f(wd[u] & 0xffff0000u);
            }
        }
    }
    // P2 slice: 8 consecutive bf16 (persistent)
    float p2f[8];
    {
        uint4 q = *(const uint4*)(P2 + (size_t)bn * PD + l * 8);
        unsigned wd[4] = {q.x, q.y, q.z, q.w};
        #pragma unroll
        for (int u = 0; u < 4; u++) {
            p2f[2 * u]     = b2f(wd[u] << 16);
            p2f[2 * u + 1] = b2f(wd[u] & 0xffff0000u);
        }
    }

    const float4* rwp = (const float4*)(rw2 + l * 32);  // interleaved (w0,w1) pairs
    const float4* vwp = (const float4*)(vw2 + l * 8);
    float rb20 = rb2[0], rb21 = rb2[1], vb20 = vb2[0];

    for (int h = 0; h < HORQ; h++) {
        const float* f1p = F1 + (size_t)(b * HORQ + h) * HID + l * 16;
        const float* f2p = F2 + (size_t)(b * HORQ + h) * PD + l * 8;
        floatx2 s01 = {0.f, 0.f};
        float sv = 0.f;
        #pragma unroll
        for (int c = 0; c < 4; c++) {
            float4 f = *(const float4*)(f1p + c * 4);
            float4 ra = rwp[c * 2];       // w0[j0],w1[j0],w0[j0+1],w1[j0+1]
            float4 rb = rwp[c * 2 + 1];   // j0+2, j0+3
            float g0 = gelu_sig(f.x + p1f[c * 4 + 0]);
            float g1 = gelu_sig(f.y + p1f[c * 4 + 1]);
            float g2 = gelu_sig(f.z + p1f[c * 4 + 2]);
            float g3 = gelu_sig(f.w + p1f[c * 4 + 3]);
            s01 += (floatx2){g0, g0} * (floatx2){ra.x, ra.y};
            s01 += (floatx2){g1, g1} * (floatx2){ra.z, ra.w};
            s01 += (floatx2){g2, g2} * (floatx2){rb.x, rb.y};
            s01 += (floatx2){g3, g3} * (floatx2){rb.z, rb.w};
        }
        #pragma unroll
        for (int c = 0; c < 2; c++) {
            float4 f = *(const float4*)(f2p + c * 4);
            float4 wv4 = vwp[c];
            sv += gelu_sig(f.x + p2f[c * 4 + 0]) * wv4.x;
            sv += gelu_sig(f.y + p2f[c * 4 + 1]) * wv4.y;
            sv += gelu_sig(f.z + p2f[c * 4 + 2]) * wv4.z;
            sv += gelu_sig(f.w + p2f[c * 4 + 3]) * wv4.w;
        }
        float s0 = s01.x, s1 = s01.y;
        #pragma unroll
        for (int m = 8; m; m >>= 1) {
            s0 += __shfl_xor(s0, m, 16);
            s1 += __shfl_xor(s1, m, 16);
            sv += __shfl_xor(sv, m, 16);
        }
        if (l == 0) {
            float rx = 0.1f * tanh_fast(s0 + rb20);
            float ry = 0.1f * tanh_fast(s1 + rb21);
            int bh = b * HORQ + h;
            out1[((size_t)bn * HORQ + h) * 2 + 0] = ap[bh * 2 + 0] + rx;
            out1[((size_t)bn * HORQ + h) * 2 + 1] = ap[bh * 2 + 1] + ry;
            out2[(size_t)bn * HORQ + h] = sv + vb20;
        }
    }
}

extern "C" void kernel_launch(void* const* d_in, const int* in_sizes, int n_in,
                              void* d_out, int out_size, void* d_ws, size_t ws_size,
                              hipStream_t stream)
{
    const float* obs  = (const float*)d_in[0];
    const int*   vis  = (const int*)d_in[1];
    const float* rel  = (const float*)d_in[2];
    const float* aobs = (const float*)d_in[3];
    const float* avel = (const float*)d_in[4];
    const float* lnw = (const float*)d_in[6];
    const float* lnb = (const float*)d_in[7];
    const float* ew1 = (const float*)d_in[8];
    const float* eb1 = (const float*)d_in[9];
    const float* ew2 = (const float*)d_in[10];
    const float* eb2 = (const float*)d_in[11];
    const float* te  = (const float*)d_in[12];
    const float* aw  = (const float*)d_in[13];
    const float* ab  = (const float*)d_in[14];
    const float* qw  = (const float*)d_in[15];
    const float* qbias = (const float*)d_in[16];
    const float* ipw = (const float*)d_in[17];
    const float* ipb = (const float*)d_in[18];
    const float* opw = (const float*)d_in[19];
    const float* opb = (const float*)d_in[20];
    const float* ahw = (const float*)d_in[21];
    const float* ahb = (const float*)d_in[22];
    const float* rw1 = (const float*)d_in[23];
    const float* rb1 = (const float*)d_in[24];
    const float* rw2 = (const float*)d_in[25];
    const float* rb2 = (const float*)d_in[26];
    const float* vw1 = (const float*)d_in[27];
    const float* vb1 = (const float*)d_in[28];
    const float* vw2 = (const float*)d_in[29];
    const float* vb2 = (const float*)d_in[30];
    const float* shw = (const float*)d_in[31];
    const float* shb = (const float*)d_in[32];

    float* W = (float*)d_ws;
    size_t o = 0;
    float* Wk  = W + o; o += (size_t)PD * HID;
    float* Wv  = W + o; o += (size_t)PD * HID;
    float* bk  = W + o; o += HID;
    float* bv  = W + o; o += HID;
    float* qb_ = W + o; o += (size_t)BB * HORQ * HID;
    float* F1  = W + o; o += (size_t)BB * HORQ * HID;
    float* F2  = W + o; o += (size_t)BB * HORQ * PD;
    float* dl  = W + o; o += (size_t)BB * HORQ * 2;
    float* pm  = W + o; o += (size_t)BB * NHD * NC2 * 8;
    float* pl  = W + o; o += (size_t)BB * NHD * NC2 * 8;
    float* po  = W + o; o += (size_t)BB * NHD * NC2 * 8 * DH;
    ushort_t* kb   = (ushort_t*)(W + o); o += (size_t)BB * NN * HID / 2;
    ushort_t* vbuf = (ushort_t*)(W + o); o += (size_t)BB * NN * HID / 2;
    ushort_t* P1   = (ushort_t*)(W + o); o += (size_t)BB * NN * HID / 2;
    ushort_t* P2   = (ushort_t*)(W + o); o += (size_t)BB * NN * PD / 2;
    short* Sf = (short*)(W + o);
    short* Wfrag  = Sf;
    short* w1frag = Sf + 114688;
    short* w2frag = Sf + 114688 + 8192;

    float* out0 = (float*)d_out;
    float* out1 = out0 + BB * HORQ * 2;
    float* out2 = out1 + (size_t)BB * NN * HORQ * 2;
    float* out3 = out2 + (size_t)BB * NN * HORQ;

    k_fuse<<<PD + 1, 256, 0, stream>>>(qw, qbias, ipw, ipb, Wk, Wv, bk, bv);
    k_prep<<<72 + 64, 256, 0, stream>>>(Wk, Wv, rw1, vw1, ew1, ew2,
                                        aobs, avel, te, aw, ab, ipw, ipb,
                                        Wfrag, w1frag, w2frag, qb_);
    k_main<<<BB * NN / 32, 256, 0, stream>>>(obs, vis, rel, lnw, lnb, eb1, eb2,
                                             Wfrag, w1frag, w2frag, bk, bv, rw1,
                                             kb, vbuf, P1, P2);
    k_att<<<BB * NHD * NC2, 256, 0, stream>>>(qb_, kb, vbuf, pm, pl, po);
    k_attfut<<<BB * HORQ, 256, 0, stream>>>(pm, pl, po, opw, opb, rw1, rb1, vw1, vb1,
                                            shw, shb, ahw, ahb, F1, F2, dl, out3);
    k_cum<<<1, 64, 0, stream>>>(aobs, dl, out0);
    k_fin<<<BB * NN / 16, 256, 0, stream>>>(F1, F2, P1, P2, rw2, rb2, vw2, vb2,
                                            out0, out1, out2);
}